// Round 6
// baseline (911.545 us; speedup 1.0000x reference)
//
#include <hip/hip_runtime.h>
#include <cstdint>

#define N_NODES 50000   // multiple of 8: every 8-node wave group is full
#define N_EDGES 800000
#define N_PAIRS 200000
#define IN_DIM 128
#define HID 64
#define SCAN_BLOCKS ((N_NODES + 255) / 256)   // 196

__device__ __forceinline__ float wave_reduce_sum(float v) {
    #pragma unroll
    for (int off = 32; off > 0; off >>= 1) v += __shfl_xor(v, off, 64);
    return v;
}

// z = x @ W, fused el/er. 256 threads = 4 waves; each wave computes 8 node rows,
// lane j = output column. W staged in LDS once per block (read from global once
// per block, not once per wave). x rows read as wave-uniform float4 broadcasts.
template <int K>
__global__ __launch_bounds__(256) void gemm_el_er(
    const float* __restrict__ x, const float* __restrict__ W,
    const float* __restrict__ al, const float* __restrict__ ar,
    float* __restrict__ z, float* __restrict__ el, float* __restrict__ er)
{
    __shared__ float Ws[K * HID];
    const int j = threadIdx.x;   // 0..63
    const int w = threadIdx.y;   // 0..3
    const int tid = w * 64 + j;
    for (int idx = tid; idx < K * HID; idx += 256) Ws[idx] = W[idx];
    __syncthreads();

    const int i0 = (blockIdx.x * 4 + w) * 8;
    if (i0 >= N_NODES) return;   // N_NODES % 8 == 0: waves are all-or-nothing

    float acc[8] = {0.f, 0.f, 0.f, 0.f, 0.f, 0.f, 0.f, 0.f};
    const float* xbase = x + (size_t)i0 * K;

    for (int k = 0; k < K; k += 4) {
        float4 xv[8];
        #pragma unroll
        for (int m = 0; m < 8; ++m)
            xv[m] = *(const float4*)&xbase[m * K + k];   // wave-uniform -> broadcast
        #pragma unroll
        for (int kk = 0; kk < 4; ++kk) {
            const float wv = Ws[(k + kk) * HID + j];     // lane j -> bank j%32, conflict-free
            #pragma unroll
            for (int m = 0; m < 8; ++m) {
                const float xs = ((const float*)&xv[m])[kk];
                acc[m] = fmaf(xs, wv, acc[m]);
            }
        }
    }

    const float alj = al[j], arj = ar[j];
    #pragma unroll
    for (int m = 0; m < 8; ++m) {
        z[(size_t)(i0 + m) * HID + j] = acc[m];
        float vel = wave_reduce_sum(acc[m] * alj);
        float ver = wave_reduce_sum(acc[m] * arj);
        if (j == 0) { el[i0 + m] = vel; er[i0 + m] = ver; }
    }
}

// ---- degree histogram ----
__global__ __launch_bounds__(256) void hist_kernel(
    const int* __restrict__ dst, int* __restrict__ deg)
{
    int e = blockIdx.x * blockDim.x + threadIdx.x;
    if (e < N_EDGES) atomicAdd(&deg[dst[e]], 1);
}

// device-wide exclusive scan, 3 launches
__global__ __launch_bounds__(256) void scan1(
    const int* __restrict__ deg, int* __restrict__ ex, int* __restrict__ bsums)
{
    __shared__ int sh[256];
    const int t = threadIdx.x;
    const int i = blockIdx.x * 256 + t;
    int v = (i < N_NODES) ? deg[i] : 0;
    sh[t] = v; __syncthreads();
    #pragma unroll
    for (int off = 1; off < 256; off <<= 1) {
        int x = sh[t];
        int a = (t >= off) ? sh[t - off] : 0;
        __syncthreads();
        sh[t] = x + a;
        __syncthreads();
    }
    if (i < N_NODES) ex[i] = sh[t] - v;
    if (t == 255) bsums[blockIdx.x] = sh[255];
}

__global__ __launch_bounds__(256) void scan2(int* __restrict__ bsums)
{
    __shared__ int sh[256];
    const int t = threadIdx.x;
    int v = (t < SCAN_BLOCKS) ? bsums[t] : 0;
    sh[t] = v; __syncthreads();
    #pragma unroll
    for (int off = 1; off < 256; off <<= 1) {
        int x = sh[t];
        int a = (t >= off) ? sh[t - off] : 0;
        __syncthreads();
        sh[t] = x + a;
        __syncthreads();
    }
    if (t < SCAN_BLOCKS) bsums[t] = sh[t] - v;
    if (t == 255) bsums[SCAN_BLOCKS] = sh[255];
}

__global__ __launch_bounds__(256) void scan3(
    const int* __restrict__ ex, const int* __restrict__ bsums,
    int* __restrict__ row_start, int* __restrict__ cursor)
{
    const int i = blockIdx.x * 256 + threadIdx.x;
    if (i < N_NODES) {
        int r = ex[i] + bsums[blockIdx.x];
        row_start[i] = r; cursor[i] = r;
    }
    if (i == 0) row_start[N_NODES] = bsums[SCAN_BLOCKS];
}

__global__ __launch_bounds__(256) void scatter_kernel(
    const int* __restrict__ src, const int* __restrict__ dst,
    int* __restrict__ cursor, int* __restrict__ csr_src)
{
    int e = blockIdx.x * blockDim.x + threadIdx.x;
    if (e >= N_EDGES) return;
    int d = dst[e];
    int pos = atomicAdd(&cursor[d], 1);
    csr_src[pos] = src[e];
}

// fused per-dst-node softmax-aggregate + relu. One wave per node.
// Lane layout: es = lane>>4 (edge slot 0..3), f4 = lane&15 (feature float4 quad).
// Softmax computed WITHOUT max-shift (shift-invariant; |e| <~ 8 so exp is safe in fp32).
__global__ __launch_bounds__(256) void node_agg(
    const int* __restrict__ row_start, const int* __restrict__ csr_src,
    const float* __restrict__ el, const float* __restrict__ er,
    const float* __restrict__ z, float* __restrict__ h)
{
    const int lane = threadIdx.x;
    const int i = blockIdx.x * 4 + threadIdx.y;
    if (i >= N_NODES) return;
    const int rb = row_start[i], re = row_start[i + 1];
    const float er_i = er[i];
    const int es = lane >> 4;
    const int f4 = lane & 15;

    float4 acc = make_float4(0.f, 0.f, 0.f, 0.f);
    float den = 0.f;
    for (int e0 = rb; e0 < re; e0 += 4) {
        int e = e0 + es;
        if (e < re) {
            int s = csr_src[e];
            float x = el[s] + er_i;
            float lr = x > 0.f ? x : 0.2f * x;
            float ex = __expf(lr);
            const float4 zv = *(const float4*)&z[(size_t)s * HID + f4 * 4];
            acc.x = fmaf(ex, zv.x, acc.x);
            acc.y = fmaf(ex, zv.y, acc.y);
            acc.z = fmaf(ex, zv.z, acc.z);
            acc.w = fmaf(ex, zv.w, acc.w);
            den += ex;
        }
    }
    #pragma unroll
    for (int off = 16; off < 64; off <<= 1) {
        acc.x += __shfl_xor(acc.x, off, 64);
        acc.y += __shfl_xor(acc.y, off, 64);
        acc.z += __shfl_xor(acc.z, off, 64);
        acc.w += __shfl_xor(acc.w, off, 64);
        den   += __shfl_xor(den,   off, 64);
    }
    if (es == 0) {
        float inv = 1.f / fmaxf(den, 1e-9f);
        float4 r;
        r.x = fmaxf(acc.x * inv, 0.f);
        r.y = fmaxf(acc.y * inv, 0.f);
        r.z = fmaxf(acc.z * inv, 0.f);
        r.w = fmaxf(acc.w * inv, 0.f);
        *(float4*)&h[(size_t)i * HID + f4 * 4] = r;
    }
}

// 2 pairs per wave; membership via CSR row scan of dst's neighbor list.
__global__ __launch_bounds__(256) void pair_head(
    const int* __restrict__ ps, const int* __restrict__ pd,
    const float* __restrict__ h, const float* __restrict__ Wc,
    const float* __restrict__ bc, const int* __restrict__ row_start,
    const int* __restrict__ csr_src, float* __restrict__ out)
{
    const int lane = threadIdx.x;
    const int p = blockIdx.x * 8 + threadIdx.y * 2 + (lane >> 5);
    if (p >= N_PAIRS) return;
    const int r = lane & 31;
    const int which = r >> 4;
    const int f4 = r & 15;
    int s = ps[p], d = pd[p];
    int node = which ? d : s;
    const float4 hv = *(const float4*)&h[(size_t)node * HID + f4 * 4];
    const float4 wv = *(const float4*)&Wc[which * HID + f4 * 4];
    float v = hv.x * wv.x + hv.y * wv.y + hv.z * wv.z + hv.w * wv.w;

    const int rb = row_start[d], re = row_start[d + 1];
    int found = 0;
    for (int e = rb + r; e < re; e += 32) found |= (csr_src[e] == s) ? 1 : 0;

    #pragma unroll
    for (int off = 1; off < 32; off <<= 1) {
        v += __shfl_xor(v, off, 64);
        found |= __shfl_xor(found, off, 64);
    }
    if (r == 0) {
        float sg = 1.f / (1.f + __expf(-(v + bc[0])));
        out[p] = found ? sg : 0.f;
    }
}

extern "C" void kernel_launch(void* const* d_in, const int* in_sizes, int n_in,
                              void* d_out, int out_size, void* d_ws, size_t ws_size,
                              hipStream_t stream)
{
    const float* feat = (const float*)d_in[0];
    const float* W1   = (const float*)d_in[1];
    const float* al1  = (const float*)d_in[2];
    const float* ar1  = (const float*)d_in[3];
    const float* W2   = (const float*)d_in[4];
    const float* al2  = (const float*)d_in[5];
    const float* ar2  = (const float*)d_in[6];
    const float* Wc   = (const float*)d_in[7];
    const float* bc   = (const float*)d_in[8];
    const int* src    = (const int*)d_in[9];
    const int* dst    = (const int*)d_in[10];
    const int* psrc   = (const int*)d_in[11];
    const int* pdst   = (const int*)d_in[12];
    float* out = (float*)d_out;

    char* ws = (char*)d_ws;
    float* z  = (float*)ws;               ws += (size_t)N_NODES * HID * 4;
    float* h1 = (float*)ws;               ws += (size_t)N_NODES * HID * 4;
    float* el = (float*)ws;               ws += (size_t)N_NODES * 4;
    float* er = (float*)ws;               ws += (size_t)N_NODES * 4;
    int* deg = (int*)ws;                  ws += (size_t)N_NODES * 4;
    int* cursor = (int*)ws;               ws += (size_t)N_NODES * 4;
    int* row_start = (int*)ws;            ws += (size_t)(N_NODES + 1) * 4;
    int* ex_scan = (int*)ws;              ws += (size_t)N_NODES * 4;
    int* bsums = (int*)ws;                ws += (size_t)(SCAN_BLOCKS + 1) * 4;
    ws = (char*)(((uintptr_t)ws + 255) & ~(uintptr_t)255);
    int* csr_src = (int*)ws;              ws += (size_t)N_EDGES * 4;

    dim3 b64x4(64, 4);
    const int EB = (N_EDGES + 255) / 256;
    const int GB = (N_NODES + 31) / 32;   // gemm blocks: 32 nodes per block

    // ---- graph structure (once per call) ----
    hipMemsetAsync(deg, 0, (size_t)N_NODES * 4, stream);
    hist_kernel<<<EB, 256, 0, stream>>>(dst, deg);
    scan1<<<SCAN_BLOCKS, 256, 0, stream>>>(deg, ex_scan, bsums);
    scan2<<<1, 256, 0, stream>>>(bsums);
    scan3<<<SCAN_BLOCKS, 256, 0, stream>>>(ex_scan, bsums, row_start, cursor);
    scatter_kernel<<<EB, 256, 0, stream>>>(src, dst, cursor, csr_src);

    // ---- layer 1 ----
    gemm_el_er<IN_DIM><<<GB, b64x4, 0, stream>>>(feat, W1, al1, ar1, z, el, er);
    node_agg<<<(N_NODES + 3) / 4, b64x4, 0, stream>>>(row_start, csr_src, el, er, z, h1);

    // ---- layer 2 ----
    gemm_el_er<HID><<<GB, b64x4, 0, stream>>>(h1, W2, al2, ar2, z, el, er);
    node_agg<<<(N_NODES + 3) / 4, b64x4, 0, stream>>>(row_start, csr_src, el, er, z, h1);

    // ---- pair head (membership via CSR row scan) ----
    pair_head<<<N_PAIRS / 8, b64x4, 0, stream>>>(psrc, pdst, h1, Wc, bc, row_start, csr_src, out);
}

// Round 7
// 368.857 us; speedup vs baseline: 2.4713x; 2.4713x over previous
//
#include <hip/hip_runtime.h>
#include <cstdint>

#define N_NODES 50000   // multiple of 8: every 8-node wave group is full
#define N_EDGES 800000
#define N_PAIRS 200000
#define IN_DIM 128
#define HID 64
#define SCAN_BLOCKS ((N_NODES + 255) / 256)   // 196

__device__ __forceinline__ float wave_reduce_sum(float v) {
    #pragma unroll
    for (int off = 32; off > 0; off >>= 1) v += __shfl_xor(v, off, 64);
    return v;
}

// z = x @ W, fused el/er. 256 threads = 4 waves; each wave computes 8 node rows,
// lane j = output column. W staged in LDS once per block. x rows read as
// wave-uniform float4 loads (single base + immediate offsets, L1-served).
// NOTE: k-loop MUST stay rolled (#pragma unroll 1) — full unroll spills to
// scratch (R6: VGPR=256, 1.3 GB scratch traffic, 570 µs).
template <int K>
__global__ __launch_bounds__(256) void gemm_el_er(
    const float* __restrict__ x, const float* __restrict__ W,
    const float* __restrict__ al, const float* __restrict__ ar,
    float* __restrict__ z, float* __restrict__ el, float* __restrict__ er)
{
    __shared__ float Ws[K * HID];
    const int j = threadIdx.x;   // 0..63
    const int w = threadIdx.y;   // 0..3
    const int tid = w * 64 + j;
    #pragma unroll 1
    for (int idx = tid; idx < K * HID; idx += 256) Ws[idx] = W[idx];
    __syncthreads();

    const int i0 = (blockIdx.x * 4 + w) * 8;
    if (i0 >= N_NODES) return;   // N_NODES % 8 == 0: waves are all-or-nothing

    float acc[8] = {0.f, 0.f, 0.f, 0.f, 0.f, 0.f, 0.f, 0.f};
    const float* xbase = x + (size_t)i0 * K;

    #pragma unroll 1
    for (int k = 0; k < K; k += 4) {
        float4 xv[8];
        #pragma unroll
        for (int m = 0; m < 8; ++m)
            xv[m] = *(const float4*)&xbase[m * K + k];   // wave-uniform
        #pragma unroll
        for (int kk = 0; kk < 4; ++kk) {
            const float wv = Ws[(k + kk) * HID + j];     // 2-way bank alias: free
            #pragma unroll
            for (int m = 0; m < 8; ++m) {
                const float xs = ((const float*)&xv[m])[kk];
                acc[m] = fmaf(xs, wv, acc[m]);
            }
        }
    }

    const float alj = al[j], arj = ar[j];
    #pragma unroll 1
    for (int m = 0; m < 8; ++m) {
        z[(size_t)(i0 + m) * HID + j] = acc[m];
        float vel = wave_reduce_sum(acc[m] * alj);
        float ver = wave_reduce_sum(acc[m] * arj);
        if (j == 0) { el[i0 + m] = vel; er[i0 + m] = ver; }
    }
}

// ---- degree histogram ----
__global__ __launch_bounds__(256) void hist_kernel(
    const int* __restrict__ dst, int* __restrict__ deg)
{
    int e = blockIdx.x * blockDim.x + threadIdx.x;
    if (e < N_EDGES) atomicAdd(&deg[dst[e]], 1);
}

// device-wide exclusive scan, 3 launches
__global__ __launch_bounds__(256) void scan1(
    const int* __restrict__ deg, int* __restrict__ ex, int* __restrict__ bsums)
{
    __shared__ int sh[256];
    const int t = threadIdx.x;
    const int i = blockIdx.x * 256 + t;
    int v = (i < N_NODES) ? deg[i] : 0;
    sh[t] = v; __syncthreads();
    #pragma unroll
    for (int off = 1; off < 256; off <<= 1) {
        int x = sh[t];
        int a = (t >= off) ? sh[t - off] : 0;
        __syncthreads();
        sh[t] = x + a;
        __syncthreads();
    }
    if (i < N_NODES) ex[i] = sh[t] - v;
    if (t == 255) bsums[blockIdx.x] = sh[255];
}

__global__ __launch_bounds__(256) void scan2(int* __restrict__ bsums)
{
    __shared__ int sh[256];
    const int t = threadIdx.x;
    int v = (t < SCAN_BLOCKS) ? bsums[t] : 0;
    sh[t] = v; __syncthreads();
    #pragma unroll
    for (int off = 1; off < 256; off <<= 1) {
        int x = sh[t];
        int a = (t >= off) ? sh[t - off] : 0;
        __syncthreads();
        sh[t] = x + a;
        __syncthreads();
    }
    if (t < SCAN_BLOCKS) bsums[t] = sh[t] - v;
    if (t == 255) bsums[SCAN_BLOCKS] = sh[255];
}

__global__ __launch_bounds__(256) void scan3(
    const int* __restrict__ ex, const int* __restrict__ bsums,
    int* __restrict__ row_start, int* __restrict__ cursor)
{
    const int i = blockIdx.x * 256 + threadIdx.x;
    if (i < N_NODES) {
        int r = ex[i] + bsums[blockIdx.x];
        row_start[i] = r; cursor[i] = r;
    }
    if (i == 0) row_start[N_NODES] = bsums[SCAN_BLOCKS];
}

__global__ __launch_bounds__(256) void scatter_kernel(
    const int* __restrict__ src, const int* __restrict__ dst,
    int* __restrict__ cursor, int* __restrict__ csr_src)
{
    int e = blockIdx.x * blockDim.x + threadIdx.x;
    if (e >= N_EDGES) return;
    int d = dst[e];
    int pos = atomicAdd(&cursor[d], 1);
    csr_src[pos] = src[e];
}

// fused per-dst-node softmax-aggregate + relu. One wave per node.
// Lane layout: es = lane>>4 (edge slot 0..3), f4 = lane&15 (feature float4 quad).
// Softmax computed WITHOUT max-shift (shift-invariant; |e| <~ 8 so exp is safe in fp32).
__global__ __launch_bounds__(256) void node_agg(
    const int* __restrict__ row_start, const int* __restrict__ csr_src,
    const float* __restrict__ el, const float* __restrict__ er,
    const float* __restrict__ z, float* __restrict__ h)
{
    const int lane = threadIdx.x;
    const int i = blockIdx.x * 4 + threadIdx.y;
    if (i >= N_NODES) return;
    const int rb = row_start[i], re = row_start[i + 1];
    const float er_i = er[i];
    const int es = lane >> 4;
    const int f4 = lane & 15;

    float4 acc = make_float4(0.f, 0.f, 0.f, 0.f);
    float den = 0.f;
    for (int e0 = rb; e0 < re; e0 += 4) {
        int e = e0 + es;
        if (e < re) {
            int s = csr_src[e];
            float x = el[s] + er_i;
            float lr = x > 0.f ? x : 0.2f * x;
            float ex = __expf(lr);
            const float4 zv = *(const float4*)&z[(size_t)s * HID + f4 * 4];
            acc.x = fmaf(ex, zv.x, acc.x);
            acc.y = fmaf(ex, zv.y, acc.y);
            acc.z = fmaf(ex, zv.z, acc.z);
            acc.w = fmaf(ex, zv.w, acc.w);
            den += ex;
        }
    }
    #pragma unroll
    for (int off = 16; off < 64; off <<= 1) {
        acc.x += __shfl_xor(acc.x, off, 64);
        acc.y += __shfl_xor(acc.y, off, 64);
        acc.z += __shfl_xor(acc.z, off, 64);
        acc.w += __shfl_xor(acc.w, off, 64);
        den   += __shfl_xor(den,   off, 64);
    }
    if (es == 0) {
        float inv = 1.f / fmaxf(den, 1e-9f);
        float4 r;
        r.x = fmaxf(acc.x * inv, 0.f);
        r.y = fmaxf(acc.y * inv, 0.f);
        r.z = fmaxf(acc.z * inv, 0.f);
        r.w = fmaxf(acc.w * inv, 0.f);
        *(float4*)&h[(size_t)i * HID + f4 * 4] = r;
    }
}

// 2 pairs per wave; membership via CSR row scan of dst's neighbor list.
__global__ __launch_bounds__(256) void pair_head(
    const int* __restrict__ ps, const int* __restrict__ pd,
    const float* __restrict__ h, const float* __restrict__ Wc,
    const float* __restrict__ bc, const int* __restrict__ row_start,
    const int* __restrict__ csr_src, float* __restrict__ out)
{
    const int lane = threadIdx.x;
    const int p = blockIdx.x * 8 + threadIdx.y * 2 + (lane >> 5);
    if (p >= N_PAIRS) return;
    const int r = lane & 31;
    const int which = r >> 4;
    const int f4 = r & 15;
    int s = ps[p], d = pd[p];
    int node = which ? d : s;
    const float4 hv = *(const float4*)&h[(size_t)node * HID + f4 * 4];
    const float4 wv = *(const float4*)&Wc[which * HID + f4 * 4];
    float v = hv.x * wv.x + hv.y * wv.y + hv.z * wv.z + hv.w * wv.w;

    const int rb = row_start[d], re = row_start[d + 1];
    int found = 0;
    for (int e = rb + r; e < re; e += 32) found |= (csr_src[e] == s) ? 1 : 0;

    #pragma unroll
    for (int off = 1; off < 32; off <<= 1) {
        v += __shfl_xor(v, off, 64);
        found |= __shfl_xor(found, off, 64);
    }
    if (r == 0) {
        float sg = 1.f / (1.f + __expf(-(v + bc[0])));
        out[p] = found ? sg : 0.f;
    }
}

extern "C" void kernel_launch(void* const* d_in, const int* in_sizes, int n_in,
                              void* d_out, int out_size, void* d_ws, size_t ws_size,
                              hipStream_t stream)
{
    const float* feat = (const float*)d_in[0];
    const float* W1   = (const float*)d_in[1];
    const float* al1  = (const float*)d_in[2];
    const float* ar1  = (const float*)d_in[3];
    const float* W2   = (const float*)d_in[4];
    const float* al2  = (const float*)d_in[5];
    const float* ar2  = (const float*)d_in[6];
    const float* Wc   = (const float*)d_in[7];
    const float* bc   = (const float*)d_in[8];
    const int* src    = (const int*)d_in[9];
    const int* dst    = (const int*)d_in[10];
    const int* psrc   = (const int*)d_in[11];
    const int* pdst   = (const int*)d_in[12];
    float* out = (float*)d_out;

    char* ws = (char*)d_ws;
    float* z  = (float*)ws;               ws += (size_t)N_NODES * HID * 4;
    float* h1 = (float*)ws;               ws += (size_t)N_NODES * HID * 4;
    float* el = (float*)ws;               ws += (size_t)N_NODES * 4;
    float* er = (float*)ws;               ws += (size_t)N_NODES * 4;
    int* deg = (int*)ws;                  ws += (size_t)N_NODES * 4;
    int* cursor = (int*)ws;               ws += (size_t)N_NODES * 4;
    int* row_start = (int*)ws;            ws += (size_t)(N_NODES + 1) * 4;
    int* ex_scan = (int*)ws;              ws += (size_t)N_NODES * 4;
    int* bsums = (int*)ws;                ws += (size_t)(SCAN_BLOCKS + 1) * 4;
    ws = (char*)(((uintptr_t)ws + 255) & ~(uintptr_t)255);
    int* csr_src = (int*)ws;              ws += (size_t)N_EDGES * 4;

    dim3 b64x4(64, 4);
    const int EB = (N_EDGES + 255) / 256;
    const int GB = (N_NODES + 31) / 32;   // gemm blocks: 32 nodes per block

    // ---- graph structure (once per call) ----
    hipMemsetAsync(deg, 0, (size_t)N_NODES * 4, stream);
    hist_kernel<<<EB, 256, 0, stream>>>(dst, deg);
    scan1<<<SCAN_BLOCKS, 256, 0, stream>>>(deg, ex_scan, bsums);
    scan2<<<1, 256, 0, stream>>>(bsums);
    scan3<<<SCAN_BLOCKS, 256, 0, stream>>>(ex_scan, bsums, row_start, cursor);
    scatter_kernel<<<EB, 256, 0, stream>>>(src, dst, cursor, csr_src);

    // ---- layer 1 ----
    gemm_el_er<IN_DIM><<<GB, b64x4, 0, stream>>>(feat, W1, al1, ar1, z, el, er);
    node_agg<<<(N_NODES + 3) / 4, b64x4, 0, stream>>>(row_start, csr_src, el, er, z, h1);

    // ---- layer 2 ----
    gemm_el_er<HID><<<GB, b64x4, 0, stream>>>(h1, W2, al2, ar2, z, el, er);
    node_agg<<<(N_NODES + 3) / 4, b64x4, 0, stream>>>(row_start, csr_src, el, er, z, h1);

    // ---- pair head (membership via CSR row scan) ----
    pair_head<<<N_PAIRS / 8, b64x4, 0, stream>>>(psrc, pdst, h1, Wc, bc, row_start, csr_src, out);
}

// Round 8
// 368.193 us; speedup vs baseline: 2.4757x; 1.0018x over previous
//
#include <hip/hip_runtime.h>
#include <cstdint>

#define N_NODES 50000   // multiple of 8: every 8-node wave group is full
#define N_EDGES 800000
#define N_PAIRS 200000
#define IN_DIM 128
#define HID 64
#define SCAN_BLOCKS ((N_NODES + 255) / 256)   // 196

__device__ __forceinline__ float wave_reduce_sum(float v) {
    #pragma unroll
    for (int off = 32; off > 0; off >>= 1) v += __shfl_xor(v, off, 64);
    return v;
}

// z = x @ W, fused el/er. 4 waves/block; each wave computes 8 node rows,
// lane j = output column. W staged in LDS once per block.
// k-loop: rolled (full unroll spills — R6: VGPR=256, 1.3 GB scratch) but
// 2-stage ping-pong pipelined (R7: unpipelined rolled loop = exposed latency).
template <int K>
__global__ __launch_bounds__(256) void gemm_el_er(
    const float* __restrict__ x, const float* __restrict__ W,
    const float* __restrict__ al, const float* __restrict__ ar,
    float* __restrict__ z, float* __restrict__ el, float* __restrict__ er)
{
    __shared__ float Ws[K * HID];
    const int j = threadIdx.x;   // 0..63
    const int w = threadIdx.y;   // 0..3
    const int tid = w * 64 + j;
    #pragma unroll 1
    for (int idx = tid; idx < K * HID / 4; idx += 256)
        *(float4*)&Ws[idx * 4] = *(const float4*)&W[idx * 4];
    __syncthreads();

    const int i0 = (blockIdx.x * 4 + w) * 8;
    if (i0 >= N_NODES) return;   // N_NODES % 8 == 0

    float acc[8] = {0.f, 0.f, 0.f, 0.f, 0.f, 0.f, 0.f, 0.f};
    const float* xbase = x + (size_t)i0 * K;

    float4 xa[8], xb[8];
    #pragma unroll
    for (int m = 0; m < 8; ++m) xa[m] = *(const float4*)&xbase[m * K];

    #pragma unroll 1
    for (int k = 0; k < K; k += 8) {
        // prefetch second half of this chunk while computing first half
        #pragma unroll
        for (int m = 0; m < 8; ++m) xb[m] = *(const float4*)&xbase[m * K + k + 4];
        #pragma unroll
        for (int kk = 0; kk < 4; ++kk) {
            const float wv = Ws[(k + kk) * HID + j];
            #pragma unroll
            for (int m = 0; m < 8; ++m)
                acc[m] = fmaf(((const float*)&xa[m])[kk], wv, acc[m]);
        }
        // prefetch next chunk's first half while computing second half
        const int kn = (k + 8 < K) ? (k + 8) : 0;   // last trip: dummy reload
        #pragma unroll
        for (int m = 0; m < 8; ++m) xa[m] = *(const float4*)&xbase[m * K + kn];
        #pragma unroll
        for (int kk = 0; kk < 4; ++kk) {
            const float wv = Ws[(k + 4 + kk) * HID + j];
            #pragma unroll
            for (int m = 0; m < 8; ++m)
                acc[m] = fmaf(((const float*)&xb[m])[kk], wv, acc[m]);
        }
    }

    const float alj = al[j], arj = ar[j];
    #pragma unroll 1
    for (int m = 0; m < 8; ++m) {
        z[(size_t)(i0 + m) * HID + j] = acc[m];
        float vel = wave_reduce_sum(acc[m] * alj);
        float ver = wave_reduce_sum(acc[m] * arj);
        if (j == 0) { el[i0 + m] = vel; er[i0 + m] = ver; }
    }
}

// ---- degree histogram ----
__global__ __launch_bounds__(256) void hist_kernel(
    const int* __restrict__ dst, int* __restrict__ deg)
{
    int e = blockIdx.x * blockDim.x + threadIdx.x;
    if (e < N_EDGES) atomicAdd(&deg[dst[e]], 1);
}

// device-wide exclusive scan, 3 launches
__global__ __launch_bounds__(256) void scan1(
    const int* __restrict__ deg, int* __restrict__ ex, int* __restrict__ bsums)
{
    __shared__ int sh[256];
    const int t = threadIdx.x;
    const int i = blockIdx.x * 256 + t;
    int v = (i < N_NODES) ? deg[i] : 0;
    sh[t] = v; __syncthreads();
    #pragma unroll
    for (int off = 1; off < 256; off <<= 1) {
        int x = sh[t];
        int a = (t >= off) ? sh[t - off] : 0;
        __syncthreads();
        sh[t] = x + a;
        __syncthreads();
    }
    if (i < N_NODES) ex[i] = sh[t] - v;
    if (t == 255) bsums[blockIdx.x] = sh[255];
}

__global__ __launch_bounds__(256) void scan2(int* __restrict__ bsums)
{
    __shared__ int sh[256];
    const int t = threadIdx.x;
    int v = (t < SCAN_BLOCKS) ? bsums[t] : 0;
    sh[t] = v; __syncthreads();
    #pragma unroll
    for (int off = 1; off < 256; off <<= 1) {
        int x = sh[t];
        int a = (t >= off) ? sh[t - off] : 0;
        __syncthreads();
        sh[t] = x + a;
        __syncthreads();
    }
    if (t < SCAN_BLOCKS) bsums[t] = sh[t] - v;
    if (t == 255) bsums[SCAN_BLOCKS] = sh[255];
}

__global__ __launch_bounds__(256) void scan3(
    const int* __restrict__ ex, const int* __restrict__ bsums,
    int* __restrict__ row_start, int* __restrict__ cursor)
{
    const int i = blockIdx.x * 256 + threadIdx.x;
    if (i < N_NODES) {
        int r = ex[i] + bsums[blockIdx.x];
        row_start[i] = r; cursor[i] = r;
    }
    if (i == 0) row_start[N_NODES] = bsums[SCAN_BLOCKS];
}

__global__ __launch_bounds__(256) void scatter_kernel(
    const int* __restrict__ src, const int* __restrict__ dst,
    int* __restrict__ cursor, int* __restrict__ csr_src)
{
    int e = blockIdx.x * blockDim.x + threadIdx.x;
    if (e >= N_EDGES) return;
    int d = dst[e];
    int pos = atomicAdd(&cursor[d], 1);
    csr_src[pos] = src[e];
}

// fused per-dst-node softmax-aggregate + relu. One wave per node.
// Lane layout: es = lane>>4 (edge slot 0..3), f4 = lane&15 (feature float4 quad).
// Softmax computed WITHOUT max-shift (shift-invariant; |e| <~ 8 so exp is safe in fp32).
__global__ __launch_bounds__(256) void node_agg(
    const int* __restrict__ row_start, const int* __restrict__ csr_src,
    const float* __restrict__ el, const float* __restrict__ er,
    const float* __restrict__ z, float* __restrict__ h)
{
    const int lane = threadIdx.x;
    const int i = blockIdx.x * 4 + threadIdx.y;
    if (i >= N_NODES) return;
    const int rb = row_start[i], re = row_start[i + 1];
    const float er_i = er[i];
    const int es = lane >> 4;
    const int f4 = lane & 15;

    float4 acc = make_float4(0.f, 0.f, 0.f, 0.f);
    float den = 0.f;
    for (int e0 = rb; e0 < re; e0 += 4) {
        int e = e0 + es;
        if (e < re) {
            int s = csr_src[e];
            float x = el[s] + er_i;
            float lr = x > 0.f ? x : 0.2f * x;
            float ex = __expf(lr);
            const float4 zv = *(const float4*)&z[(size_t)s * HID + f4 * 4];
            acc.x = fmaf(ex, zv.x, acc.x);
            acc.y = fmaf(ex, zv.y, acc.y);
            acc.z = fmaf(ex, zv.z, acc.z);
            acc.w = fmaf(ex, zv.w, acc.w);
            den += ex;
        }
    }
    #pragma unroll
    for (int off = 16; off < 64; off <<= 1) {
        acc.x += __shfl_xor(acc.x, off, 64);
        acc.y += __shfl_xor(acc.y, off, 64);
        acc.z += __shfl_xor(acc.z, off, 64);
        acc.w += __shfl_xor(acc.w, off, 64);
        den   += __shfl_xor(den,   off, 64);
    }
    if (es == 0) {
        float inv = 1.f / fmaxf(den, 1e-9f);
        float4 r;
        r.x = fmaxf(acc.x * inv, 0.f);
        r.y = fmaxf(acc.y * inv, 0.f);
        r.z = fmaxf(acc.z * inv, 0.f);
        r.w = fmaxf(acc.w * inv, 0.f);
        *(float4*)&h[(size_t)i * HID + f4 * 4] = r;
    }
}

// 2 pairs per wave; membership via CSR row scan of dst's neighbor list.
__global__ __launch_bounds__(256) void pair_head(
    const int* __restrict__ ps, const int* __restrict__ pd,
    const float* __restrict__ h, const float* __restrict__ Wc,
    const float* __restrict__ bc, const int* __restrict__ row_start,
    const int* __restrict__ csr_src, float* __restrict__ out)
{
    const int lane = threadIdx.x;
    const int p = blockIdx.x * 8 + threadIdx.y * 2 + (lane >> 5);
    if (p >= N_PAIRS) return;
    const int r = lane & 31;
    const int which = r >> 4;
    const int f4 = r & 15;
    int s = ps[p], d = pd[p];
    int node = which ? d : s;
    const float4 hv = *(const float4*)&h[(size_t)node * HID + f4 * 4];
    const float4 wv = *(const float4*)&Wc[which * HID + f4 * 4];
    float v = hv.x * wv.x + hv.y * wv.y + hv.z * wv.z + hv.w * wv.w;

    const int rb = row_start[d], re = row_start[d + 1];
    int found = 0;
    for (int e = rb + r; e < re; e += 32) found |= (csr_src[e] == s) ? 1 : 0;

    #pragma unroll
    for (int off = 1; off < 32; off <<= 1) {
        v += __shfl_xor(v, off, 64);
        found |= __shfl_xor(found, off, 64);
    }
    if (r == 0) {
        float sg = 1.f / (1.f + __expf(-(v + bc[0])));
        out[p] = found ? sg : 0.f;
    }
}

extern "C" void kernel_launch(void* const* d_in, const int* in_sizes, int n_in,
                              void* d_out, int out_size, void* d_ws, size_t ws_size,
                              hipStream_t stream)
{
    const float* feat = (const float*)d_in[0];
    const float* W1   = (const float*)d_in[1];
    const float* al1  = (const float*)d_in[2];
    const float* ar1  = (const float*)d_in[3];
    const float* W2   = (const float*)d_in[4];
    const float* al2  = (const float*)d_in[5];
    const float* ar2  = (const float*)d_in[6];
    const float* Wc   = (const float*)d_in[7];
    const float* bc   = (const float*)d_in[8];
    const int* src    = (const int*)d_in[9];
    const int* dst    = (const int*)d_in[10];
    const int* psrc   = (const int*)d_in[11];
    const int* pdst   = (const int*)d_in[12];
    float* out = (float*)d_out;

    char* ws = (char*)d_ws;
    float* z  = (float*)ws;               ws += (size_t)N_NODES * HID * 4;
    float* h1 = (float*)ws;               ws += (size_t)N_NODES * HID * 4;
    float* el = (float*)ws;               ws += (size_t)N_NODES * 4;
    float* er = (float*)ws;               ws += (size_t)N_NODES * 4;
    int* deg = (int*)ws;                  ws += (size_t)N_NODES * 4;
    int* cursor = (int*)ws;               ws += (size_t)N_NODES * 4;
    int* row_start = (int*)ws;            ws += (size_t)(N_NODES + 1) * 4;
    int* ex_scan = (int*)ws;              ws += (size_t)N_NODES * 4;
    int* bsums = (int*)ws;                ws += (size_t)(SCAN_BLOCKS + 1) * 4;
    ws = (char*)(((uintptr_t)ws + 255) & ~(uintptr_t)255);
    int* csr_src = (int*)ws;              ws += (size_t)N_EDGES * 4;

    dim3 b64x4(64, 4);
    const int EB = (N_EDGES + 255) / 256;
    const int GB = (N_NODES + 31) / 32;   // gemm blocks: 32 nodes per block

    // ---- graph structure (once per call) ----
    hipMemsetAsync(deg, 0, (size_t)N_NODES * 4, stream);
    hist_kernel<<<EB, 256, 0, stream>>>(dst, deg);
    scan1<<<SCAN_BLOCKS, 256, 0, stream>>>(deg, ex_scan, bsums);
    scan2<<<1, 256, 0, stream>>>(bsums);
    scan3<<<SCAN_BLOCKS, 256, 0, stream>>>(ex_scan, bsums, row_start, cursor);
    scatter_kernel<<<EB, 256, 0, stream>>>(src, dst, cursor, csr_src);

    // ---- layer 1 ----
    gemm_el_er<IN_DIM><<<GB, b64x4, 0, stream>>>(feat, W1, al1, ar1, z, el, er);
    node_agg<<<(N_NODES + 3) / 4, b64x4, 0, stream>>>(row_start, csr_src, el, er, z, h1);

    // ---- layer 2 ----
    gemm_el_er<HID><<<GB, b64x4, 0, stream>>>(h1, W2, al2, ar2, z, el, er);
    node_agg<<<(N_NODES + 3) / 4, b64x4, 0, stream>>>(row_start, csr_src, el, er, z, h1);

    // ---- pair head (membership via CSR row scan) ----
    pair_head<<<N_PAIRS / 8, b64x4, 0, stream>>>(psrc, pdst, h1, Wc, bc, row_start, csr_src, out);
}

// Round 9
// 300.012 us; speedup vs baseline: 3.0384x; 1.2273x over previous
//
#include <hip/hip_runtime.h>
#include <cstdint>

#define N_NODES 50000
#define N_EDGES 800000
#define N_PAIRS 200000
#define IN_DIM 128
#define HID 64
#define SCAN_BLOCKS ((N_NODES + 255) / 256)   // 196
#define N_WAVES_GEMM (N_NODES / 16)           // 3125 (50000 = 3125*16 exactly)

typedef __attribute__((ext_vector_type(8))) short bf16x8;
typedef __attribute__((ext_vector_type(4))) float f32x4;

__device__ __forceinline__ float wave_reduce_sum(float v) {
    #pragma unroll
    for (int off = 32; off > 0; off >>= 1) v += __shfl_xor(v, off, 64);
    return v;
}

// RNE float->bf16 bits
__device__ __forceinline__ unsigned short bf16_rne(float f) {
    unsigned u = __float_as_uint(f);
    unsigned t = u + 0x7FFFu + ((u >> 16) & 1u);
    return (unsigned short)(t >> 16);
}

// ---- W pre-swizzle into MFMA B-fragment layout, split hi/lo bf16 ----
// B-frag (16x16x32): lane holds B[k = quad*8 + jj][n = lane&15], jj=0..7.
// buffer index: (((ks*4 + tile)*64) + lane)*8 + jj
__global__ __launch_bounds__(256) void prep_w(
    const float* __restrict__ W1, const float* __restrict__ W2,
    unsigned short* __restrict__ w1hi, unsigned short* __restrict__ w1lo,
    unsigned short* __restrict__ w2hi, unsigned short* __restrict__ w2lo)
{
    int tid = blockIdx.x * 256 + threadIdx.x;
    if (tid < 8192) {   // W1: 4 ksteps x 4 tiles x 64 lanes x 8
        int jj = tid & 7, lane = (tid >> 3) & 63, t = (tid >> 9) & 3, ks = tid >> 11;
        int k = ks * 32 + (lane >> 4) * 8 + jj;
        int n = t * 16 + (lane & 15);
        float f = W1[k * HID + n];
        unsigned short hi = bf16_rne(f);
        float fhi = __uint_as_float(((unsigned)hi) << 16);
        w1hi[tid] = hi;
        w1lo[tid] = bf16_rne(f - fhi);
    }
    if (tid < 4096) {   // W2: 2 ksteps x 4 tiles x 64 lanes x 8
        int jj = tid & 7, lane = (tid >> 3) & 63, t = (tid >> 9) & 3, ks = tid >> 11;
        int k = ks * 32 + (lane >> 4) * 8 + jj;
        int n = t * 16 + (lane & 15);
        float f = W2[k * HID + n];
        unsigned short hi = bf16_rne(f);
        float fhi = __uint_as_float(((unsigned)hi) << 16);
        w2hi[tid] = hi;
        w2lo[tid] = bf16_rne(f - fhi);
    }
}

// z = x @ W via mfma_f32_16x16x32_bf16, split-bf16 (hi*hi + hi*lo + lo*hi).
// One wave per 16 node rows; 4 tiles cover the 64 output cols.
// A-frag: A[m = lane&15][k = quad*8 + jj]. C/D: col = lane&15, row = quad*4 + reg.
// Fused el/er epilogue via 16-lane quad reductions.
template <int NKS>   // K = NKS*32
__global__ __launch_bounds__(256) void gemm_mfma(
    const float* __restrict__ x,
    const unsigned short* __restrict__ whi, const unsigned short* __restrict__ wlo,
    const float* __restrict__ al, const float* __restrict__ ar,
    float* __restrict__ z, float* __restrict__ el, float* __restrict__ er)
{
    const int lane = threadIdx.x;
    const int wave = blockIdx.x * 4 + threadIdx.y;
    if (wave >= N_WAVES_GEMM) return;
    const int i0 = wave * 16;
    const int m = lane & 15, quad = lane >> 4;

    f32x4 acc[4] = {{0.f,0.f,0.f,0.f},{0.f,0.f,0.f,0.f},{0.f,0.f,0.f,0.f},{0.f,0.f,0.f,0.f}};
    const float* xrow = x + (size_t)(i0 + m) * (NKS * 32);

    #pragma unroll 1
    for (int ks = 0; ks < NKS; ++ks) {
        // A-frag: 8 consecutive floats at k0 + quad*8, split to hi/lo bf16
        const float4 xv0 = *(const float4*)&xrow[ks * 32 + quad * 8];
        const float4 xv1 = *(const float4*)&xrow[ks * 32 + quad * 8 + 4];
        float xs[8] = {xv0.x, xv0.y, xv0.z, xv0.w, xv1.x, xv1.y, xv1.z, xv1.w};
        bf16x8 ahi, alo;
        #pragma unroll
        for (int jj = 0; jj < 8; ++jj) {
            unsigned short hb = bf16_rne(xs[jj]);
            float fhi = __uint_as_float(((unsigned)hb) << 16);
            ahi[jj] = (short)hb;
            alo[jj] = (short)bf16_rne(xs[jj] - fhi);
        }
        #pragma unroll
        for (int t = 0; t < 4; ++t) {
            const bf16x8 bhi = *(const bf16x8*)&whi[(((ks * 4 + t) * 64) + lane) * 8];
            const bf16x8 blo = *(const bf16x8*)&wlo[(((ks * 4 + t) * 64) + lane) * 8];
            acc[t] = __builtin_amdgcn_mfma_f32_16x16x32_bf16(ahi, bhi, acc[t], 0, 0, 0);
            acc[t] = __builtin_amdgcn_mfma_f32_16x16x32_bf16(ahi, blo, acc[t], 0, 0, 0);
            acc[t] = __builtin_amdgcn_mfma_f32_16x16x32_bf16(alo, bhi, acc[t], 0, 0, 0);
        }
    }

    // epilogue: store z, reduce el/er per output row
    #pragma unroll
    for (int r = 0; r < 4; ++r) {
        const int row = quad * 4 + r;
        float se = 0.f, sr = 0.f;
        #pragma unroll
        for (int t = 0; t < 4; ++t) {
            float v = acc[t][r];
            z[(size_t)(i0 + row) * HID + t * 16 + m] = v;
            se = fmaf(v, al[t * 16 + m], se);
            sr = fmaf(v, ar[t * 16 + m], sr);
        }
        #pragma unroll
        for (int off = 1; off < 16; off <<= 1) {
            se += __shfl_xor(se, off, 64);
            sr += __shfl_xor(sr, off, 64);
        }
        if (m == 0) { el[i0 + row] = se; er[i0 + row] = sr; }
    }
}

// ---- degree histogram ----
__global__ __launch_bounds__(256) void hist_kernel(
    const int* __restrict__ dst, int* __restrict__ deg)
{
    int e = blockIdx.x * blockDim.x + threadIdx.x;
    if (e < N_EDGES) atomicAdd(&deg[dst[e]], 1);
}

// device-wide exclusive scan, 3 launches
__global__ __launch_bounds__(256) void scan1(
    const int* __restrict__ deg, int* __restrict__ ex, int* __restrict__ bsums)
{
    __shared__ int sh[256];
    const int t = threadIdx.x;
    const int i = blockIdx.x * 256 + t;
    int v = (i < N_NODES) ? deg[i] : 0;
    sh[t] = v; __syncthreads();
    #pragma unroll
    for (int off = 1; off < 256; off <<= 1) {
        int x = sh[t];
        int a = (t >= off) ? sh[t - off] : 0;
        __syncthreads();
        sh[t] = x + a;
        __syncthreads();
    }
    if (i < N_NODES) ex[i] = sh[t] - v;
    if (t == 255) bsums[blockIdx.x] = sh[255];
}

__global__ __launch_bounds__(256) void scan2(int* __restrict__ bsums)
{
    __shared__ int sh[256];
    const int t = threadIdx.x;
    int v = (t < SCAN_BLOCKS) ? bsums[t] : 0;
    sh[t] = v; __syncthreads();
    #pragma unroll
    for (int off = 1; off < 256; off <<= 1) {
        int x = sh[t];
        int a = (t >= off) ? sh[t - off] : 0;
        __syncthreads();
        sh[t] = x + a;
        __syncthreads();
    }
    if (t < SCAN_BLOCKS) bsums[t] = sh[t] - v;
    if (t == 255) bsums[SCAN_BLOCKS] = sh[255];
}

__global__ __launch_bounds__(256) void scan3(
    const int* __restrict__ ex, const int* __restrict__ bsums,
    int* __restrict__ row_start, int* __restrict__ cursor)
{
    const int i = blockIdx.x * 256 + threadIdx.x;
    if (i < N_NODES) {
        int r = ex[i] + bsums[blockIdx.x];
        row_start[i] = r; cursor[i] = r;
    }
    if (i == 0) row_start[N_NODES] = bsums[SCAN_BLOCKS];
}

__global__ __launch_bounds__(256) void scatter_kernel(
    const int* __restrict__ src, const int* __restrict__ dst,
    int* __restrict__ cursor, int* __restrict__ csr_src)
{
    int e = blockIdx.x * blockDim.x + threadIdx.x;
    if (e >= N_EDGES) return;
    int d = dst[e];
    int pos = atomicAdd(&cursor[d], 1);
    csr_src[pos] = src[e];
}

// fused per-dst-node softmax-aggregate + relu. One wave per node.
// Lane layout: es = lane>>4 (edge slot 0..3), f4 = lane&15 (feature float4 quad).
// Softmax without max-shift (shift-invariant; |e| small, fp32-safe).
__global__ __launch_bounds__(256) void node_agg(
    const int* __restrict__ row_start, const int* __restrict__ csr_src,
    const float* __restrict__ el, const float* __restrict__ er,
    const float* __restrict__ z, float* __restrict__ h)
{
    const int lane = threadIdx.x;
    const int i = blockIdx.x * 4 + threadIdx.y;
    if (i >= N_NODES) return;
    const int rb = row_start[i], re = row_start[i + 1];
    const float er_i = er[i];
    const int es = lane >> 4;
    const int f4 = lane & 15;

    float4 acc = make_float4(0.f, 0.f, 0.f, 0.f);
    float den = 0.f;
    for (int e0 = rb; e0 < re; e0 += 4) {
        int e = e0 + es;
        if (e < re) {
            int s = csr_src[e];
            float x = el[s] + er_i;
            float lr = x > 0.f ? x : 0.2f * x;
            float ex = __expf(lr);
            const float4 zv = *(const float4*)&z[(size_t)s * HID + f4 * 4];
            acc.x = fmaf(ex, zv.x, acc.x);
            acc.y = fmaf(ex, zv.y, acc.y);
            acc.z = fmaf(ex, zv.z, acc.z);
            acc.w = fmaf(ex, zv.w, acc.w);
            den += ex;
        }
    }
    #pragma unroll
    for (int off = 16; off < 64; off <<= 1) {
        acc.x += __shfl_xor(acc.x, off, 64);
        acc.y += __shfl_xor(acc.y, off, 64);
        acc.z += __shfl_xor(acc.z, off, 64);
        acc.w += __shfl_xor(acc.w, off, 64);
        den   += __shfl_xor(den,   off, 64);
    }
    if (es == 0) {
        float inv = 1.f / fmaxf(den, 1e-9f);
        float4 r;
        r.x = fmaxf(acc.x * inv, 0.f);
        r.y = fmaxf(acc.y * inv, 0.f);
        r.z = fmaxf(acc.z * inv, 0.f);
        r.w = fmaxf(acc.w * inv, 0.f);
        *(float4*)&h[(size_t)i * HID + f4 * 4] = r;
    }
}

// 2 pairs per wave; membership via CSR row scan of dst's neighbor list.
__global__ __launch_bounds__(256) void pair_head(
    const int* __restrict__ ps, const int* __restrict__ pd,
    const float* __restrict__ h, const float* __restrict__ Wc,
    const float* __restrict__ bc, const int* __restrict__ row_start,
    const int* __restrict__ csr_src, float* __restrict__ out)
{
    const int lane = threadIdx.x;
    const int p = blockIdx.x * 8 + threadIdx.y * 2 + (lane >> 5);
    if (p >= N_PAIRS) return;
    const int r = lane & 31;
    const int which = r >> 4;
    const int f4 = r & 15;
    int s = ps[p], d = pd[p];
    int node = which ? d : s;
    const float4 hv = *(const float4*)&h[(size_t)node * HID + f4 * 4];
    const float4 wv = *(const float4*)&Wc[which * HID + f4 * 4];
    float v = hv.x * wv.x + hv.y * wv.y + hv.z * wv.z + hv.w * wv.w;

    const int rb = row_start[d], re = row_start[d + 1];
    int found = 0;
    for (int e = rb + r; e < re; e += 32) found |= (csr_src[e] == s) ? 1 : 0;

    #pragma unroll
    for (int off = 1; off < 32; off <<= 1) {
        v += __shfl_xor(v, off, 64);
        found |= __shfl_xor(found, off, 64);
    }
    if (r == 0) {
        float sg = 1.f / (1.f + __expf(-(v + bc[0])));
        out[p] = found ? sg : 0.f;
    }
}

extern "C" void kernel_launch(void* const* d_in, const int* in_sizes, int n_in,
                              void* d_out, int out_size, void* d_ws, size_t ws_size,
                              hipStream_t stream)
{
    const float* feat = (const float*)d_in[0];
    const float* W1   = (const float*)d_in[1];
    const float* al1  = (const float*)d_in[2];
    const float* ar1  = (const float*)d_in[3];
    const float* W2   = (const float*)d_in[4];
    const float* al2  = (const float*)d_in[5];
    const float* ar2  = (const float*)d_in[6];
    const float* Wc   = (const float*)d_in[7];
    const float* bc   = (const float*)d_in[8];
    const int* src    = (const int*)d_in[9];
    const int* dst    = (const int*)d_in[10];
    const int* psrc   = (const int*)d_in[11];
    const int* pdst   = (const int*)d_in[12];
    float* out = (float*)d_out;

    char* ws = (char*)d_ws;
    float* z  = (float*)ws;               ws += (size_t)N_NODES * HID * 4;
    float* h1 = (float*)ws;               ws += (size_t)N_NODES * HID * 4;
    float* el = (float*)ws;               ws += (size_t)N_NODES * 4;
    float* er = (float*)ws;               ws += (size_t)N_NODES * 4;
    int* deg = (int*)ws;                  ws += (size_t)N_NODES * 4;
    int* cursor = (int*)ws;               ws += (size_t)N_NODES * 4;
    int* row_start = (int*)ws;            ws += (size_t)(N_NODES + 1) * 4;
    int* ex_scan = (int*)ws;              ws += (size_t)N_NODES * 4;
    int* bsums = (int*)ws;                ws += (size_t)(SCAN_BLOCKS + 1) * 4;
    ws = (char*)(((uintptr_t)ws + 255) & ~(uintptr_t)255);
    int* csr_src = (int*)ws;              ws += (size_t)N_EDGES * 4;
    unsigned short* w1hi = (unsigned short*)ws;  ws += 8192 * 2;
    unsigned short* w1lo = (unsigned short*)ws;  ws += 8192 * 2;
    unsigned short* w2hi = (unsigned short*)ws;  ws += 4096 * 2;
    unsigned short* w2lo = (unsigned short*)ws;  ws += 4096 * 2;

    dim3 b64x4(64, 4);
    const int EB = (N_EDGES + 255) / 256;
    const int MB = (N_WAVES_GEMM + 3) / 4;   // 782 blocks, 4 waves each

    // ---- graph structure + W fragment prep (once per call) ----
    hipMemsetAsync(deg, 0, (size_t)N_NODES * 4, stream);
    prep_w<<<32, 256, 0, stream>>>(W1, W2, w1hi, w1lo, w2hi, w2lo);
    hist_kernel<<<EB, 256, 0, stream>>>(dst, deg);
    scan1<<<SCAN_BLOCKS, 256, 0, stream>>>(deg, ex_scan, bsums);
    scan2<<<1, 256, 0, stream>>>(bsums);
    scan3<<<SCAN_BLOCKS, 256, 0, stream>>>(ex_scan, bsums, row_start, cursor);
    scatter_kernel<<<EB, 256, 0, stream>>>(src, dst, cursor, csr_src);

    // ---- layer 1 ----
    gemm_mfma<4><<<MB, b64x4, 0, stream>>>(feat, w1hi, w1lo, al1, ar1, z, el, er);
    node_agg<<<(N_NODES + 3) / 4, b64x4, 0, stream>>>(row_start, csr_src, el, er, z, h1);

    // ---- layer 2 ----
    gemm_mfma<2><<<MB, b64x4, 0, stream>>>(h1, w2hi, w2lo, al2, ar2, z, el, er);
    node_agg<<<(N_NODES + 3) / 4, b64x4, 0, stream>>>(row_start, csr_src, el, er, z, h1);

    // ---- pair head (membership via CSR row scan) ----
    pair_head<<<N_PAIRS / 8, b64x4, 0, stream>>>(psrc, pdst, h1, Wc, bc, row_start, csr_src, out);
}

// Round 10
// 234.872 us; speedup vs baseline: 3.8810x; 1.2773x over previous
//
#include <hip/hip_runtime.h>
#include <cstdint>

#define N_NODES 50000
#define N_EDGES 800000
#define N_PAIRS 200000
#define IN_DIM 128
#define HID 64
#define N_WAVES_GEMM (N_NODES / 16)           // 3125
#define NB1 196                               // high-byte bins AND edge chunks
#define CHUNK ((N_EDGES + NB1 - 1) / NB1)     // 4082
#define MHIST (NB1 * NB1)                     // 38416
#define SBG ((MHIST + 255) / 256)             // 151 scan blocks

typedef __attribute__((ext_vector_type(8))) short bf16x8;
typedef __attribute__((ext_vector_type(4))) float f32x4;

__device__ __forceinline__ unsigned short bf16_rne(float f) {
    unsigned u = __float_as_uint(f);
    unsigned t = u + 0x7FFFu + ((u >> 16) & 1u);
    return (unsigned short)(t >> 16);
}

// ---- W pre-swizzle into MFMA B-fragment layout, split hi/lo bf16 ----
__global__ __launch_bounds__(256) void prep_w(
    const float* __restrict__ W1, const float* __restrict__ W2,
    unsigned short* __restrict__ w1hi, unsigned short* __restrict__ w1lo,
    unsigned short* __restrict__ w2hi, unsigned short* __restrict__ w2lo)
{
    int tid = blockIdx.x * 256 + threadIdx.x;
    if (tid < 8192) {
        int jj = tid & 7, lane = (tid >> 3) & 63, t = (tid >> 9) & 3, ks = tid >> 11;
        int k = ks * 32 + (lane >> 4) * 8 + jj;
        int n = t * 16 + (lane & 15);
        float f = W1[k * HID + n];
        unsigned short hi = bf16_rne(f);
        float fhi = __uint_as_float(((unsigned)hi) << 16);
        w1hi[tid] = hi;
        w1lo[tid] = bf16_rne(f - fhi);
    }
    if (tid < 4096) {
        int jj = tid & 7, lane = (tid >> 3) & 63, t = (tid >> 9) & 3, ks = tid >> 11;
        int k = ks * 32 + (lane >> 4) * 8 + jj;
        int n = t * 16 + (lane & 15);
        float f = W2[k * HID + n];
        unsigned short hi = bf16_rne(f);
        float fhi = __uint_as_float(((unsigned)hi) << 16);
        w2hi[tid] = hi;
        w2lo[tid] = bf16_rne(f - fhi);
    }
}

// z = x @ W via mfma_f32_16x16x32_bf16, split-bf16 (hi*hi + hi*lo + lo*hi).
template <int NKS>   // K = NKS*32
__global__ __launch_bounds__(256) void gemm_mfma(
    const float* __restrict__ x,
    const unsigned short* __restrict__ whi, const unsigned short* __restrict__ wlo,
    const float* __restrict__ al, const float* __restrict__ ar,
    float* __restrict__ z, float* __restrict__ el, float* __restrict__ er)
{
    const int lane = threadIdx.x;
    const int wave = blockIdx.x * 4 + threadIdx.y;
    if (wave >= N_WAVES_GEMM) return;
    const int i0 = wave * 16;
    const int m = lane & 15, quad = lane >> 4;

    f32x4 acc[4] = {{0.f,0.f,0.f,0.f},{0.f,0.f,0.f,0.f},{0.f,0.f,0.f,0.f},{0.f,0.f,0.f,0.f}};
    const float* xrow = x + (size_t)(i0 + m) * (NKS * 32);

    #pragma unroll 1
    for (int ks = 0; ks < NKS; ++ks) {
        const float4 xv0 = *(const float4*)&xrow[ks * 32 + quad * 8];
        const float4 xv1 = *(const float4*)&xrow[ks * 32 + quad * 8 + 4];
        float xs[8] = {xv0.x, xv0.y, xv0.z, xv0.w, xv1.x, xv1.y, xv1.z, xv1.w};
        bf16x8 ahi, alo;
        #pragma unroll
        for (int jj = 0; jj < 8; ++jj) {
            unsigned short hb = bf16_rne(xs[jj]);
            float fhi = __uint_as_float(((unsigned)hb) << 16);
            ahi[jj] = (short)hb;
            alo[jj] = (short)bf16_rne(xs[jj] - fhi);
        }
        #pragma unroll
        for (int t = 0; t < 4; ++t) {
            const bf16x8 bhi = *(const bf16x8*)&whi[(((ks * 4 + t) * 64) + lane) * 8];
            const bf16x8 blo = *(const bf16x8*)&wlo[(((ks * 4 + t) * 64) + lane) * 8];
            acc[t] = __builtin_amdgcn_mfma_f32_16x16x32_bf16(ahi, bhi, acc[t], 0, 0, 0);
            acc[t] = __builtin_amdgcn_mfma_f32_16x16x32_bf16(ahi, blo, acc[t], 0, 0, 0);
            acc[t] = __builtin_amdgcn_mfma_f32_16x16x32_bf16(alo, bhi, acc[t], 0, 0, 0);
        }
    }

    #pragma unroll
    for (int r = 0; r < 4; ++r) {
        const int row = quad * 4 + r;
        float se = 0.f, sr = 0.f;
        #pragma unroll
        for (int t = 0; t < 4; ++t) {
            float v = acc[t][r];
            z[(size_t)(i0 + row) * HID + t * 16 + m] = v;
            se = fmaf(v, al[t * 16 + m], se);
            sr = fmaf(v, ar[t * 16 + m], sr);
        }
        #pragma unroll
        for (int off = 1; off < 16; off <<= 1) {
            se += __shfl_xor(se, off, 64);
            sr += __shfl_xor(sr, off, 64);
        }
        if (m == 0) { el[i0 + row] = se; er[i0 + row] = sr; }
    }
}

// ---- MSD sort pass 1: per-block histogram of dst>>8 ----
__global__ __launch_bounds__(256) void hist_hi(
    const int* __restrict__ dst, int* __restrict__ histHi)
{
    __shared__ int hist[256];
    const int t = threadIdx.x, b = blockIdx.x;
    hist[t] = 0; __syncthreads();
    const int beg = b * CHUNK, end = min(beg + CHUNK, N_EDGES);
    for (int e = beg + t; e < end; e += 256) atomicAdd(&hist[dst[e] >> 8], 1);
    __syncthreads();
    if (t < NB1) histHi[t * NB1 + b] = hist[t];
}

// generic device-wide exclusive scan (3 launches)
__global__ __launch_bounds__(256) void scan1g(
    const int* __restrict__ in, int* __restrict__ ex, int* __restrict__ bsums, int n)
{
    __shared__ int sh[256];
    const int t = threadIdx.x;
    const int i = blockIdx.x * 256 + t;
    int v = (i < n) ? in[i] : 0;
    sh[t] = v; __syncthreads();
    #pragma unroll
    for (int off = 1; off < 256; off <<= 1) {
        int x = sh[t];
        int a = (t >= off) ? sh[t - off] : 0;
        __syncthreads();
        sh[t] = x + a;
        __syncthreads();
    }
    if (i < n) ex[i] = sh[t] - v;
    if (t == 255) bsums[blockIdx.x] = sh[255];
}

__global__ __launch_bounds__(256) void scan2g(int* __restrict__ bsums, int nb)
{
    __shared__ int sh[256];
    const int t = threadIdx.x;
    int v = (t < nb) ? bsums[t] : 0;
    sh[t] = v; __syncthreads();
    #pragma unroll
    for (int off = 1; off < 256; off <<= 1) {
        int x = sh[t];
        int a = (t >= off) ? sh[t - off] : 0;
        __syncthreads();
        sh[t] = x + a;
        __syncthreads();
    }
    if (t < nb) bsums[t] = sh[t] - v;
}

__global__ __launch_bounds__(256) void scan3g(
    int* __restrict__ ex, const int* __restrict__ bsums, int n)
{
    const int i = blockIdx.x * 256 + threadIdx.x;
    if (i < n) ex[i] += bsums[blockIdx.x];
}

// ---- MSD sort pass 1 scatter: (src,dst) packed u32 to high-byte buckets ----
// per-(bin,block) runs are contiguous -> ~2 dirty lines per run.
__global__ __launch_bounds__(256) void scatter_hi(
    const int* __restrict__ src, const int* __restrict__ dst,
    const int* __restrict__ histOff, unsigned* __restrict__ pairs)
{
    __shared__ int base[256];
    const int t = threadIdx.x, b = blockIdx.x;
    if (t < NB1) base[t] = histOff[t * NB1 + b];
    __syncthreads();
    const int beg = b * CHUNK, end = min(beg + CHUNK, N_EDGES);
    for (int e = beg + t; e < end; e += 256) {
        int s = src[e], d = dst[e];
        int pos = atomicAdd(&base[d >> 8], 1);
        pairs[pos] = ((unsigned)s << 16) | (unsigned)d;   // both ids < 2^16
    }
}

// ---- MSD sort pass 2: one block per 256-node segment. LDS low-byte hist +
// scan gives row_start for the segment's nodes AND the in-segment scatter
// (writes land in a ~16 KB L2-hot window). Non-stable is fine (order within
// a dst only affects fp32 summation order).
__global__ __launch_bounds__(256) void seg_sort(
    const unsigned* __restrict__ pairs, const int* __restrict__ histOff,
    int* __restrict__ row_start, int* __restrict__ csr_src)
{
    __shared__ int hist[256], sc[256], offs[256];
    const int t = threadIdx.x, b = blockIdx.x;
    const int segStart = histOff[b * NB1];
    const int segEnd = (b == NB1 - 1) ? N_EDGES : histOff[(b + 1) * NB1];
    hist[t] = 0; __syncthreads();
    for (int i = segStart + t; i < segEnd; i += 256)
        atomicAdd(&hist[pairs[i] & 255], 1);
    __syncthreads();
    int v = hist[t]; sc[t] = v; __syncthreads();
    #pragma unroll
    for (int off = 1; off < 256; off <<= 1) {
        int x = sc[t];
        int a = (t >= off) ? sc[t - off] : 0;
        __syncthreads();
        sc[t] = x + a;
        __syncthreads();
    }
    const int excl = sc[t] - v;
    offs[t] = segStart + excl;
    const int node = b * 256 + t;
    if (node <= N_NODES) row_start[node] = segStart + excl;
    __syncthreads();
    for (int i = segStart + t; i < segEnd; i += 256) {
        unsigned p = pairs[i];
        int pos = atomicAdd(&offs[p & 255], 1);
        csr_src[pos] = (int)(p >> 16);
    }
}

// fused per-dst-node softmax-aggregate + relu. One wave per node.
// es = lane>>4 (edge slot 0..3), f4 = lane&15 (float4 quad).
// 3-stage pipeline: csr_src 2 iters ahead, el/z 1 iter ahead.
__global__ __launch_bounds__(256) void node_agg(
    const int* __restrict__ row_start, const int* __restrict__ csr_src,
    const float* __restrict__ el, const float* __restrict__ er,
    const float* __restrict__ z, float* __restrict__ h)
{
    const int lane = threadIdx.x;
    const int i = blockIdx.x * 4 + threadIdx.y;
    if (i >= N_NODES) return;
    const int rb = row_start[i], re = row_start[i + 1];
    const float er_i = er[i];
    const int es = lane >> 4;
    const int f4 = lane & 15;

    float4 acc = make_float4(0.f, 0.f, 0.f, 0.f);
    float den = 0.f;

    int eA = rb + es;           bool vA = eA < re;
    int eB = rb + 4 + es;       bool vB = eB < re;
    int sA = vA ? csr_src[eA] : 0;
    int sB = vB ? csr_src[eB] : 0;
    float elA = el[sA];
    float4 zvA = *(const float4*)&z[(size_t)sA * HID + f4 * 4];

    for (int e0 = rb; e0 < re; e0 += 4) {
        const int eC = e0 + 8 + es;
        const bool vC = eC < re;
        const int sC = vC ? csr_src[eC] : 0;          // 2 ahead
        const float elB = el[sB];                      // 1 ahead
        const float4 zvB = *(const float4*)&z[(size_t)sB * HID + f4 * 4];

        float x = elA + er_i;
        float lr = x > 0.f ? x : 0.2f * x;
        float ex = vA ? __expf(lr) : 0.f;
        acc.x = fmaf(ex, zvA.x, acc.x);
        acc.y = fmaf(ex, zvA.y, acc.y);
        acc.z = fmaf(ex, zvA.z, acc.z);
        acc.w = fmaf(ex, zvA.w, acc.w);
        den += ex;

        sA = sB; vA = vB; elA = elB; zvA = zvB;
        sB = sC; vB = vC;
    }
    #pragma unroll
    for (int off = 16; off < 64; off <<= 1) {
        acc.x += __shfl_xor(acc.x, off, 64);
        acc.y += __shfl_xor(acc.y, off, 64);
        acc.z += __shfl_xor(acc.z, off, 64);
        acc.w += __shfl_xor(acc.w, off, 64);
        den   += __shfl_xor(den,   off, 64);
    }
    if (es == 0) {
        float inv = 1.f / fmaxf(den, 1e-9f);
        float4 r;
        r.x = fmaxf(acc.x * inv, 0.f);
        r.y = fmaxf(acc.y * inv, 0.f);
        r.z = fmaxf(acc.z * inv, 0.f);
        r.w = fmaxf(acc.w * inv, 0.f);
        *(float4*)&h[(size_t)i * HID + f4 * 4] = r;
    }
}

// 2 pairs per wave; membership via CSR row scan of dst's neighbor list.
__global__ __launch_bounds__(256) void pair_head(
    const int* __restrict__ ps, const int* __restrict__ pd,
    const float* __restrict__ h, const float* __restrict__ Wc,
    const float* __restrict__ bc, const int* __restrict__ row_start,
    const int* __restrict__ csr_src, float* __restrict__ out)
{
    const int lane = threadIdx.x;
    const int p = blockIdx.x * 8 + threadIdx.y * 2 + (lane >> 5);
    if (p >= N_PAIRS) return;
    const int r = lane & 31;
    const int which = r >> 4;
    const int f4 = r & 15;
    int s = ps[p], d = pd[p];
    int node = which ? d : s;
    const float4 hv = *(const float4*)&h[(size_t)node * HID + f4 * 4];
    const float4 wv = *(const float4*)&Wc[which * HID + f4 * 4];
    float v = hv.x * wv.x + hv.y * wv.y + hv.z * wv.z + hv.w * wv.w;

    const int rb = row_start[d], re = row_start[d + 1];
    int found = 0;
    for (int e = rb + r; e < re; e += 32) found |= (csr_src[e] == s) ? 1 : 0;

    #pragma unroll
    for (int off = 1; off < 32; off <<= 1) {
        v += __shfl_xor(v, off, 64);
        found |= __shfl_xor(found, off, 64);
    }
    if (r == 0) {
        float sg = 1.f / (1.f + __expf(-(v + bc[0])));
        out[p] = found ? sg : 0.f;
    }
}

extern "C" void kernel_launch(void* const* d_in, const int* in_sizes, int n_in,
                              void* d_out, int out_size, void* d_ws, size_t ws_size,
                              hipStream_t stream)
{
    const float* feat = (const float*)d_in[0];
    const float* W1   = (const float*)d_in[1];
    const float* al1  = (const float*)d_in[2];
    const float* ar1  = (const float*)d_in[3];
    const float* W2   = (const float*)d_in[4];
    const float* al2  = (const float*)d_in[5];
    const float* ar2  = (const float*)d_in[6];
    const float* Wc   = (const float*)d_in[7];
    const float* bc   = (const float*)d_in[8];
    const int* src    = (const int*)d_in[9];
    const int* dst    = (const int*)d_in[10];
    const int* psrc   = (const int*)d_in[11];
    const int* pdst   = (const int*)d_in[12];
    float* out = (float*)d_out;

    char* ws = (char*)d_ws;
    float* z  = (float*)ws;               ws += (size_t)N_NODES * HID * 4;
    float* h1 = (float*)ws;               ws += (size_t)N_NODES * HID * 4;
    float* el = (float*)ws;               ws += (size_t)N_NODES * 4;
    float* er = (float*)ws;               ws += (size_t)N_NODES * 4;
    int* row_start = (int*)ws;            ws += (size_t)(N_NODES + 1) * 4;
    int* histHi = (int*)ws;               ws += (size_t)MHIST * 4;
    int* bsumsA = (int*)ws;               ws += (size_t)(SBG + 1) * 4;
    ws = (char*)(((uintptr_t)ws + 255) & ~(uintptr_t)255);
    unsigned* pairs = (unsigned*)ws;      ws += (size_t)N_EDGES * 4;
    int* csr_src = (int*)ws;              ws += (size_t)N_EDGES * 4;
    unsigned short* w1hi = (unsigned short*)ws;  ws += 8192 * 2;
    unsigned short* w1lo = (unsigned short*)ws;  ws += 8192 * 2;
    unsigned short* w2hi = (unsigned short*)ws;  ws += 4096 * 2;
    unsigned short* w2lo = (unsigned short*)ws;  ws += 4096 * 2;

    dim3 b64x4(64, 4);
    const int MB = (N_WAVES_GEMM + 3) / 4;

    // ---- W fragment prep + CSR build via MSD 2-level sort (once per call) ----
    prep_w<<<32, 256, 0, stream>>>(W1, W2, w1hi, w1lo, w2hi, w2lo);
    hist_hi<<<NB1, 256, 0, stream>>>(dst, histHi);
    scan1g<<<SBG, 256, 0, stream>>>(histHi, histHi, bsumsA, MHIST);
    scan2g<<<1, 256, 0, stream>>>(bsumsA, SBG);
    scan3g<<<SBG, 256, 0, stream>>>(histHi, bsumsA, MHIST);
    scatter_hi<<<NB1, 256, 0, stream>>>(src, dst, histHi, pairs);
    seg_sort<<<NB1, 256, 0, stream>>>(pairs, histHi, row_start, csr_src);

    // ---- layer 1 ----
    gemm_mfma<4><<<MB, b64x4, 0, stream>>>(feat, w1hi, w1lo, al1, ar1, z, el, er);
    node_agg<<<(N_NODES + 3) / 4, b64x4, 0, stream>>>(row_start, csr_src, el, er, z, h1);

    // ---- layer 2 ----
    gemm_mfma<2><<<MB, b64x4, 0, stream>>>(h1, w2hi, w2lo, al2, ar2, z, el, er);
    node_agg<<<(N_NODES + 3) / 4, b64x4, 0, stream>>>(row_start, csr_src, el, er, z, h1);

    // ---- pair head (membership via CSR row scan) ----
    pair_head<<<N_PAIRS / 8, b64x4, 0, stream>>>(psrc, pdst, h1, Wc, bc, row_start, csr_src, out);
}

// Round 11
// 228.398 us; speedup vs baseline: 3.9910x; 1.0283x over previous
//
#include <hip/hip_runtime.h>
#include <cstdint>

#define N_NODES 50000
#define N_EDGES 800000
#define N_PAIRS 200000
#define IN_DIM 128
#define HID 64
#define N_WAVES_GEMM (N_NODES / 16)           // 3125
#define NB1 196                               // high-byte bins AND edge chunks
#define CHUNK ((N_EDGES + NB1 - 1) / NB1)     // 4082
#define MHIST (NB1 * NB1)                     // 38416
#define SBG ((MHIST + 255) / 256)             // 151 scan blocks

typedef __attribute__((ext_vector_type(8))) short bf16x8;
typedef __attribute__((ext_vector_type(4))) float f32x4;

__device__ __forceinline__ unsigned short bf16_rne(float f) {
    unsigned u = __float_as_uint(f);
    unsigned t = u + 0x7FFFu + ((u >> 16) & 1u);
    return (unsigned short)(t >> 16);
}

// ---- fused: MSD pass-1 histogram (blocks 0..195) + W fragment prep (196..227) ----
__global__ __launch_bounds__(256) void hist_prep(
    const int* __restrict__ dst, int* __restrict__ histHi,
    const float* __restrict__ W1, const float* __restrict__ W2,
    unsigned short* __restrict__ w1hi, unsigned short* __restrict__ w1lo,
    unsigned short* __restrict__ w2hi, unsigned short* __restrict__ w2lo)
{
    const int t = threadIdx.x, b = blockIdx.x;
    if (b < NB1) {
        __shared__ int hist[256];
        hist[t] = 0; __syncthreads();
        const int beg = b * CHUNK, end = min(beg + CHUNK, N_EDGES);
        for (int e = beg + t; e < end; e += 256) atomicAdd(&hist[dst[e] >> 8], 1);
        __syncthreads();
        if (t < NB1) histHi[t * NB1 + b] = hist[t];
    } else {
        int tid = (b - NB1) * 256 + t;
        if (tid < 8192) {
            int jj = tid & 7, lane = (tid >> 3) & 63, tt = (tid >> 9) & 3, ks = tid >> 11;
            int k = ks * 32 + (lane >> 4) * 8 + jj;
            int n = tt * 16 + (lane & 15);
            float f = W1[k * HID + n];
            unsigned short hi = bf16_rne(f);
            float fhi = __uint_as_float(((unsigned)hi) << 16);
            w1hi[tid] = hi;
            w1lo[tid] = bf16_rne(f - fhi);
        }
        if (tid < 4096) {
            int jj = tid & 7, lane = (tid >> 3) & 63, tt = (tid >> 9) & 3, ks = tid >> 11;
            int k = ks * 32 + (lane >> 4) * 8 + jj;
            int n = tt * 16 + (lane & 15);
            float f = W2[k * HID + n];
            unsigned short hi = bf16_rne(f);
            float fhi = __uint_as_float(((unsigned)hi) << 16);
            w2hi[tid] = hi;
            w2lo[tid] = bf16_rne(f - fhi);
        }
    }
}

// z = x @ W via mfma_f32_16x16x32_bf16, split-bf16 (hi*hi + hi*lo + lo*hi).
template <int NKS>   // K = NKS*32
__global__ __launch_bounds__(256) void gemm_mfma(
    const float* __restrict__ x,
    const unsigned short* __restrict__ whi, const unsigned short* __restrict__ wlo,
    const float* __restrict__ al, const float* __restrict__ ar,
    float* __restrict__ z, float* __restrict__ el, float* __restrict__ er)
{
    const int lane = threadIdx.x;
    const int wave = blockIdx.x * 4 + threadIdx.y;
    if (wave >= N_WAVES_GEMM) return;
    const int i0 = wave * 16;
    const int m = lane & 15, quad = lane >> 4;

    f32x4 acc[4] = {{0.f,0.f,0.f,0.f},{0.f,0.f,0.f,0.f},{0.f,0.f,0.f,0.f},{0.f,0.f,0.f,0.f}};
    const float* xrow = x + (size_t)(i0 + m) * (NKS * 32);

    #pragma unroll 1
    for (int ks = 0; ks < NKS; ++ks) {
        const float4 xv0 = *(const float4*)&xrow[ks * 32 + quad * 8];
        const float4 xv1 = *(const float4*)&xrow[ks * 32 + quad * 8 + 4];
        float xs[8] = {xv0.x, xv0.y, xv0.z, xv0.w, xv1.x, xv1.y, xv1.z, xv1.w};
        bf16x8 ahi, alo;
        #pragma unroll
        for (int jj = 0; jj < 8; ++jj) {
            unsigned short hb = bf16_rne(xs[jj]);
            float fhi = __uint_as_float(((unsigned)hb) << 16);
            ahi[jj] = (short)hb;
            alo[jj] = (short)bf16_rne(xs[jj] - fhi);
        }
        #pragma unroll
        for (int t = 0; t < 4; ++t) {
            const bf16x8 bhi = *(const bf16x8*)&whi[(((ks * 4 + t) * 64) + lane) * 8];
            const bf16x8 blo = *(const bf16x8*)&wlo[(((ks * 4 + t) * 64) + lane) * 8];
            acc[t] = __builtin_amdgcn_mfma_f32_16x16x32_bf16(ahi, bhi, acc[t], 0, 0, 0);
            acc[t] = __builtin_amdgcn_mfma_f32_16x16x32_bf16(ahi, blo, acc[t], 0, 0, 0);
            acc[t] = __builtin_amdgcn_mfma_f32_16x16x32_bf16(alo, bhi, acc[t], 0, 0, 0);
        }
    }

    #pragma unroll
    for (int r = 0; r < 4; ++r) {
        const int row = quad * 4 + r;
        float se = 0.f, sr = 0.f;
        #pragma unroll
        for (int t = 0; t < 4; ++t) {
            float v = acc[t][r];
            z[(size_t)(i0 + row) * HID + t * 16 + m] = v;
            se = fmaf(v, al[t * 16 + m], se);
            sr = fmaf(v, ar[t * 16 + m], sr);
        }
        #pragma unroll
        for (int off = 1; off < 16; off <<= 1) {
            se += __shfl_xor(se, off, 64);
            sr += __shfl_xor(sr, off, 64);
        }
        if (m == 0) { el[i0 + row] = se; er[i0 + row] = sr; }
    }
}

// generic device-wide exclusive scan (3 launches)
__global__ __launch_bounds__(256) void scan1g(
    const int* __restrict__ in, int* __restrict__ ex, int* __restrict__ bsums, int n)
{
    __shared__ int sh[256];
    const int t = threadIdx.x;
    const int i = blockIdx.x * 256 + t;
    int v = (i < n) ? in[i] : 0;
    sh[t] = v; __syncthreads();
    #pragma unroll
    for (int off = 1; off < 256; off <<= 1) {
        int x = sh[t];
        int a = (t >= off) ? sh[t - off] : 0;
        __syncthreads();
        sh[t] = x + a;
        __syncthreads();
    }
    if (i < n) ex[i] = sh[t] - v;
    if (t == 255) bsums[blockIdx.x] = sh[255];
}

__global__ __launch_bounds__(256) void scan2g(int* __restrict__ bsums, int nb)
{
    __shared__ int sh[256];
    const int t = threadIdx.x;
    int v = (t < nb) ? bsums[t] : 0;
    sh[t] = v; __syncthreads();
    #pragma unroll
    for (int off = 1; off < 256; off <<= 1) {
        int x = sh[t];
        int a = (t >= off) ? sh[t - off] : 0;
        __syncthreads();
        sh[t] = x + a;
        __syncthreads();
    }
    if (t < nb) bsums[t] = sh[t] - v;
}

__global__ __launch_bounds__(256) void scan3g(
    int* __restrict__ ex, const int* __restrict__ bsums, int n)
{
    const int i = blockIdx.x * 256 + threadIdx.x;
    if (i < n) ex[i] += bsums[blockIdx.x];
}

// ---- MSD pass 1 scatter: (src,dst) packed u32 to high-byte buckets ----
__global__ __launch_bounds__(256) void scatter_hi(
    const int* __restrict__ src, const int* __restrict__ dst,
    const int* __restrict__ histOff, unsigned* __restrict__ pairs)
{
    __shared__ int base[256];
    const int t = threadIdx.x, b = blockIdx.x;
    if (t < NB1) base[t] = histOff[t * NB1 + b];
    __syncthreads();
    const int beg = b * CHUNK, end = min(beg + CHUNK, N_EDGES);
    for (int e = beg + t; e < end; e += 256) {
        int s = src[e], d = dst[e];
        int pos = atomicAdd(&base[d >> 8], 1);
        pairs[pos] = ((unsigned)s << 16) | (unsigned)d;   // both ids < 2^16
    }
}

// ---- MSD pass 2: one block per 256-node segment; low-byte hist + scan ->
// row_start + in-segment scatter (writes stay in a ~16 KB hot window).
__global__ __launch_bounds__(256) void seg_sort(
    const unsigned* __restrict__ pairs, const int* __restrict__ histOff,
    int* __restrict__ row_start, int* __restrict__ csr_src)
{
    __shared__ int hist[256], sc[256], offs[256];
    const int t = threadIdx.x, b = blockIdx.x;
    const int segStart = histOff[b * NB1];
    const int segEnd = (b == NB1 - 1) ? N_EDGES : histOff[(b + 1) * NB1];
    hist[t] = 0; __syncthreads();
    for (int i = segStart + t; i < segEnd; i += 256)
        atomicAdd(&hist[pairs[i] & 255], 1);
    __syncthreads();
    int v = hist[t]; sc[t] = v; __syncthreads();
    #pragma unroll
    for (int off = 1; off < 256; off <<= 1) {
        int x = sc[t];
        int a = (t >= off) ? sc[t - off] : 0;
        __syncthreads();
        sc[t] = x + a;
        __syncthreads();
    }
    const int excl = sc[t] - v;
    offs[t] = segStart + excl;
    const int node = b * 256 + t;
    if (node <= N_NODES) row_start[node] = segStart + excl;
    __syncthreads();
    for (int i = segStart + t; i < segEnd; i += 256) {
        unsigned p = pairs[i];
        int pos = atomicAdd(&offs[p & 255], 1);
        csr_src[pos] = (int)(p >> 16);
    }
}

// fused per-dst-node softmax-aggregate + relu. One wave per node.
// es = lane>>3 (edge slot 0..7), fl = lane&7 (8 floats = 2 float4s per lane).
// 16 z-loads in flight per wave; 2-deep pipeline (csr 2-ahead, el/z 1-ahead).
// Softmax without max-shift (shift-invariant; |e| small, fp32-safe).
__global__ __launch_bounds__(256) void node_agg(
    const int* __restrict__ row_start, const int* __restrict__ csr_src,
    const float* __restrict__ el, const float* __restrict__ er,
    const float* __restrict__ z, float* __restrict__ h)
{
    const int lane = threadIdx.x;
    const int i = blockIdx.x * 4 + threadIdx.y;
    if (i >= N_NODES) return;
    const int rb = row_start[i], re = row_start[i + 1];
    const float er_i = er[i];
    const int es = lane >> 3;
    const int fl = lane & 7;

    float4 acc0 = make_float4(0.f, 0.f, 0.f, 0.f);
    float4 acc1 = make_float4(0.f, 0.f, 0.f, 0.f);
    float den = 0.f;

    int eA = rb + es;        bool vA = eA < re;
    int eB = eA + 8;         bool vB = eB < re;
    int sA = vA ? csr_src[eA] : 0;
    int sB = vB ? csr_src[eB] : 0;
    float elA = el[sA];
    float4 zA0 = *(const float4*)&z[(size_t)sA * HID + fl * 8];
    float4 zA1 = *(const float4*)&z[(size_t)sA * HID + fl * 8 + 4];

    for (int e0 = rb; e0 < re; e0 += 8) {
        const int eC = e0 + 16 + es;
        const bool vC = eC < re;
        const int sC = vC ? csr_src[eC] : 0;                    // 2 ahead
        const float elB = el[sB];                                // 1 ahead
        const float4 zB0 = *(const float4*)&z[(size_t)sB * HID + fl * 8];
        const float4 zB1 = *(const float4*)&z[(size_t)sB * HID + fl * 8 + 4];

        float x = elA + er_i;
        float lr = x > 0.f ? x : 0.2f * x;
        float ex = vA ? __expf(lr) : 0.f;
        acc0.x = fmaf(ex, zA0.x, acc0.x);
        acc0.y = fmaf(ex, zA0.y, acc0.y);
        acc0.z = fmaf(ex, zA0.z, acc0.z);
        acc0.w = fmaf(ex, zA0.w, acc0.w);
        acc1.x = fmaf(ex, zA1.x, acc1.x);
        acc1.y = fmaf(ex, zA1.y, acc1.y);
        acc1.z = fmaf(ex, zA1.z, acc1.z);
        acc1.w = fmaf(ex, zA1.w, acc1.w);
        den += ex;

        sA = sB; vA = vB; elA = elB; zA0 = zB0; zA1 = zB1;
        sB = sC; vB = vC;
    }
    // reduce across the 8 edge slots (lanes differing in bits 3,4,5)
    #pragma unroll
    for (int off = 8; off < 64; off <<= 1) {
        acc0.x += __shfl_xor(acc0.x, off, 64);
        acc0.y += __shfl_xor(acc0.y, off, 64);
        acc0.z += __shfl_xor(acc0.z, off, 64);
        acc0.w += __shfl_xor(acc0.w, off, 64);
        acc1.x += __shfl_xor(acc1.x, off, 64);
        acc1.y += __shfl_xor(acc1.y, off, 64);
        acc1.z += __shfl_xor(acc1.z, off, 64);
        acc1.w += __shfl_xor(acc1.w, off, 64);
        den    += __shfl_xor(den,    off, 64);
    }
    if (es == 0) {
        float inv = 1.f / fmaxf(den, 1e-9f);
        float4 r0, r1;
        r0.x = fmaxf(acc0.x * inv, 0.f);
        r0.y = fmaxf(acc0.y * inv, 0.f);
        r0.z = fmaxf(acc0.z * inv, 0.f);
        r0.w = fmaxf(acc0.w * inv, 0.f);
        r1.x = fmaxf(acc1.x * inv, 0.f);
        r1.y = fmaxf(acc1.y * inv, 0.f);
        r1.z = fmaxf(acc1.z * inv, 0.f);
        r1.w = fmaxf(acc1.w * inv, 0.f);
        *(float4*)&h[(size_t)i * HID + fl * 8] = r0;
        *(float4*)&h[(size_t)i * HID + fl * 8 + 4] = r1;
    }
}

// 2 pairs per wave; membership via CSR row scan of dst's neighbor list.
__global__ __launch_bounds__(256) void pair_head(
    const int* __restrict__ ps, const int* __restrict__ pd,
    const float* __restrict__ h, const float* __restrict__ Wc,
    const float* __restrict__ bc, const int* __restrict__ row_start,
    const int* __restrict__ csr_src, float* __restrict__ out)
{
    const int lane = threadIdx.x;
    const int p = blockIdx.x * 8 + threadIdx.y * 2 + (lane >> 5);
    if (p >= N_PAIRS) return;
    const int r = lane & 31;
    const int which = r >> 4;
    const int f4 = r & 15;
    int s = ps[p], d = pd[p];
    int node = which ? d : s;
    const float4 hv = *(const float4*)&h[(size_t)node * HID + f4 * 4];
    const float4 wv = *(const float4*)&Wc[which * HID + f4 * 4];
    float v = hv.x * wv.x + hv.y * wv.y + hv.z * wv.z + hv.w * wv.w;

    const int rb = row_start[d], re = row_start[d + 1];
    int found = 0;
    for (int e = rb + r; e < re; e += 32) found |= (csr_src[e] == s) ? 1 : 0;

    #pragma unroll
    for (int off = 1; off < 32; off <<= 1) {
        v += __shfl_xor(v, off, 64);
        found |= __shfl_xor(found, off, 64);
    }
    if (r == 0) {
        float sg = 1.f / (1.f + __expf(-(v + bc[0])));
        out[p] = found ? sg : 0.f;
    }
}

extern "C" void kernel_launch(void* const* d_in, const int* in_sizes, int n_in,
                              void* d_out, int out_size, void* d_ws, size_t ws_size,
                              hipStream_t stream)
{
    const float* feat = (const float*)d_in[0];
    const float* W1   = (const float*)d_in[1];
    const float* al1  = (const float*)d_in[2];
    const float* ar1  = (const float*)d_in[3];
    const float* W2   = (const float*)d_in[4];
    const float* al2  = (const float*)d_in[5];
    const float* ar2  = (const float*)d_in[6];
    const float* Wc   = (const float*)d_in[7];
    const float* bc   = (const float*)d_in[8];
    const int* src    = (const int*)d_in[9];
    const int* dst    = (const int*)d_in[10];
    const int* psrc   = (const int*)d_in[11];
    const int* pdst   = (const int*)d_in[12];
    float* out = (float*)d_out;

    char* ws = (char*)d_ws;
    float* z  = (float*)ws;               ws += (size_t)N_NODES * HID * 4;
    float* h1 = (float*)ws;               ws += (size_t)N_NODES * HID * 4;
    float* el = (float*)ws;               ws += (size_t)N_NODES * 4;
    float* er = (float*)ws;               ws += (size_t)N_NODES * 4;
    int* row_start = (int*)ws;            ws += (size_t)(N_NODES + 1) * 4;
    int* histHi = (int*)ws;               ws += (size_t)MHIST * 4;
    int* bsumsA = (int*)ws;               ws += (size_t)(SBG + 1) * 4;
    ws = (char*)(((uintptr_t)ws + 255) & ~(uintptr_t)255);
    unsigned* pairs = (unsigned*)ws;      ws += (size_t)N_EDGES * 4;
    int* csr_src = (int*)ws;              ws += (size_t)N_EDGES * 4;
    unsigned short* w1hi = (unsigned short*)ws;  ws += 8192 * 2;
    unsigned short* w1lo = (unsigned short*)ws;  ws += 8192 * 2;
    unsigned short* w2hi = (unsigned short*)ws;  ws += 4096 * 2;
    unsigned short* w2lo = (unsigned short*)ws;  ws += 4096 * 2;

    dim3 b64x4(64, 4);
    const int MB = (N_WAVES_GEMM + 3) / 4;

    // ---- CSR build (MSD 2-level sort) + W fragment prep, fused where possible ----
    hist_prep<<<NB1 + 32, 256, 0, stream>>>(dst, histHi, W1, W2, w1hi, w1lo, w2hi, w2lo);
    scan1g<<<SBG, 256, 0, stream>>>(histHi, histHi, bsumsA, MHIST);
    scan2g<<<1, 256, 0, stream>>>(bsumsA, SBG);
    scan3g<<<SBG, 256, 0, stream>>>(histHi, bsumsA, MHIST);
    scatter_hi<<<NB1, 256, 0, stream>>>(src, dst, histHi, pairs);
    seg_sort<<<NB1, 256, 0, stream>>>(pairs, histHi, row_start, csr_src);

    // ---- layer 1 ----
    gemm_mfma<4><<<MB, b64x4, 0, stream>>>(feat, w1hi, w1lo, al1, ar1, z, el, er);
    node_agg<<<(N_NODES + 3) / 4, b64x4, 0, stream>>>(row_start, csr_src, el, er, z, h1);

    // ---- layer 2 ----
    gemm_mfma<2><<<MB, b64x4, 0, stream>>>(h1, w2hi, w2lo, al2, ar2, z, el, er);
    node_agg<<<(N_NODES + 3) / 4, b64x4, 0, stream>>>(row_start, csr_src, el, er, z, h1);

    // ---- pair head (membership via CSR row scan) ----
    pair_head<<<N_PAIRS / 8, b64x4, 0, stream>>>(psrc, pdst, h1, Wc, bc, row_start, csr_src, out);
}

// Round 12
// 212.877 us; speedup vs baseline: 4.2820x; 1.0729x over previous
//
#include <hip/hip_runtime.h>
#include <cstdint>

#define N_NODES 50000
#define N_EDGES 800000
#define N_PAIRS 200000
#define IN_DIM 128
#define HID 64
#define N_WAVES_GEMM (N_NODES / 16)           // 3125
#define NB1 196                               // high-byte bins AND edge chunks
#define CHUNK ((N_EDGES + NB1 - 1) / NB1)     // 4082
#define MHIST (NB1 * NB1)                     // 38416
#define SBG ((MHIST + 255) / 256)             // 151 scan blocks

typedef __attribute__((ext_vector_type(8))) short bf16x8;
typedef __attribute__((ext_vector_type(4))) float f32x4;

__device__ __forceinline__ unsigned short bf16_rne(float f) {
    unsigned u = __float_as_uint(f);
    unsigned t = u + 0x7FFFu + ((u >> 16) & 1u);
    return (unsigned short)(t >> 16);
}
__device__ __forceinline__ void bf2f(unsigned u, float& a, float& b) {
    a = __uint_as_float(u << 16);
    b = __uint_as_float(u & 0xFFFF0000u);
}

// ---- fused: MSD pass-1 histogram (blocks 0..195) + W fragment prep (196..227) ----
__global__ __launch_bounds__(256) void hist_prep(
    const int* __restrict__ dst, int* __restrict__ histHi,
    const float* __restrict__ W1, const float* __restrict__ W2,
    unsigned short* __restrict__ w1hi, unsigned short* __restrict__ w1lo,
    unsigned short* __restrict__ w2hi, unsigned short* __restrict__ w2lo)
{
    const int t = threadIdx.x, b = blockIdx.x;
    if (b < NB1) {
        __shared__ int hist[256];
        hist[t] = 0; __syncthreads();
        const int beg = b * CHUNK, end = min(beg + CHUNK, N_EDGES);
        for (int e = beg + t; e < end; e += 256) atomicAdd(&hist[dst[e] >> 8], 1);
        __syncthreads();
        if (t < NB1) histHi[t * NB1 + b] = hist[t];
    } else {
        int tid = (b - NB1) * 256 + t;
        if (tid < 8192) {
            int jj = tid & 7, lane = (tid >> 3) & 63, tt = (tid >> 9) & 3, ks = tid >> 11;
            int k = ks * 32 + (lane >> 4) * 8 + jj;
            int n = tt * 16 + (lane & 15);
            float f = W1[k * HID + n];
            unsigned short hi = bf16_rne(f);
            float fhi = __uint_as_float(((unsigned)hi) << 16);
            w1hi[tid] = hi;
            w1lo[tid] = bf16_rne(f - fhi);
        }
        if (tid < 4096) {
            int jj = tid & 7, lane = (tid >> 3) & 63, tt = (tid >> 9) & 3, ks = tid >> 11;
            int k = ks * 32 + (lane >> 4) * 8 + jj;
            int n = tt * 16 + (lane & 15);
            float f = W2[k * HID + n];
            unsigned short hi = bf16_rne(f);
            float fhi = __uint_as_float(((unsigned)hi) << 16);
            w2hi[tid] = hi;
            w2lo[tid] = bf16_rne(f - fhi);
        }
    }
}

// layer-1 GEMM: fp32 x, split-bf16 A (hi*hi + hi*lo + lo*hi); z stored bf16.
__global__ __launch_bounds__(256) void gemm_mfma_f(
    const float* __restrict__ x,
    const unsigned short* __restrict__ whi, const unsigned short* __restrict__ wlo,
    const float* __restrict__ al, const float* __restrict__ ar,
    unsigned short* __restrict__ z, float* __restrict__ el, float* __restrict__ er)
{
    const int lane = threadIdx.x;
    const int wave = blockIdx.x * 4 + threadIdx.y;
    if (wave >= N_WAVES_GEMM) return;
    const int i0 = wave * 16;
    const int m = lane & 15, quad = lane >> 4;

    f32x4 acc[4] = {{0.f,0.f,0.f,0.f},{0.f,0.f,0.f,0.f},{0.f,0.f,0.f,0.f},{0.f,0.f,0.f,0.f}};
    const float* xrow = x + (size_t)(i0 + m) * IN_DIM;

    #pragma unroll 1
    for (int ks = 0; ks < 4; ++ks) {
        const float4 xv0 = *(const float4*)&xrow[ks * 32 + quad * 8];
        const float4 xv1 = *(const float4*)&xrow[ks * 32 + quad * 8 + 4];
        float xs[8] = {xv0.x, xv0.y, xv0.z, xv0.w, xv1.x, xv1.y, xv1.z, xv1.w};
        bf16x8 ahi, alo;
        #pragma unroll
        for (int jj = 0; jj < 8; ++jj) {
            unsigned short hb = bf16_rne(xs[jj]);
            float fhi = __uint_as_float(((unsigned)hb) << 16);
            ahi[jj] = (short)hb;
            alo[jj] = (short)bf16_rne(xs[jj] - fhi);
        }
        #pragma unroll
        for (int t = 0; t < 4; ++t) {
            const bf16x8 bhi = *(const bf16x8*)&whi[(((ks * 4 + t) * 64) + lane) * 8];
            const bf16x8 blo = *(const bf16x8*)&wlo[(((ks * 4 + t) * 64) + lane) * 8];
            acc[t] = __builtin_amdgcn_mfma_f32_16x16x32_bf16(ahi, bhi, acc[t], 0, 0, 0);
            acc[t] = __builtin_amdgcn_mfma_f32_16x16x32_bf16(ahi, blo, acc[t], 0, 0, 0);
            acc[t] = __builtin_amdgcn_mfma_f32_16x16x32_bf16(alo, bhi, acc[t], 0, 0, 0);
        }
    }

    #pragma unroll
    for (int r = 0; r < 4; ++r) {
        const int row = quad * 4 + r;
        float se = 0.f, sr = 0.f;
        #pragma unroll
        for (int t = 0; t < 4; ++t) {
            float v = acc[t][r];
            z[(size_t)(i0 + row) * HID + t * 16 + m] = bf16_rne(v);
            se = fmaf(v, al[t * 16 + m], se);
            sr = fmaf(v, ar[t * 16 + m], sr);
        }
        #pragma unroll
        for (int off = 1; off < 16; off <<= 1) {
            se += __shfl_xor(se, off, 64);
            sr += __shfl_xor(sr, off, 64);
        }
        if (m == 0) { el[i0 + row] = se; er[i0 + row] = sr; }
    }
}

// layer-2 GEMM: bf16 h input -> A-frag loads directly, 2 MFMAs/tile (W split only).
__global__ __launch_bounds__(256) void gemm_mfma_b(
    const unsigned short* __restrict__ x,
    const unsigned short* __restrict__ whi, const unsigned short* __restrict__ wlo,
    const float* __restrict__ al, const float* __restrict__ ar,
    unsigned short* __restrict__ z, float* __restrict__ el, float* __restrict__ er)
{
    const int lane = threadIdx.x;
    const int wave = blockIdx.x * 4 + threadIdx.y;
    if (wave >= N_WAVES_GEMM) return;
    const int i0 = wave * 16;
    const int m = lane & 15, quad = lane >> 4;

    f32x4 acc[4] = {{0.f,0.f,0.f,0.f},{0.f,0.f,0.f,0.f},{0.f,0.f,0.f,0.f},{0.f,0.f,0.f,0.f}};
    const unsigned short* xrow = x + (size_t)(i0 + m) * HID;

    #pragma unroll 1
    for (int ks = 0; ks < 2; ++ks) {
        const bf16x8 a = *(const bf16x8*)&xrow[ks * 32 + quad * 8];
        #pragma unroll
        for (int t = 0; t < 4; ++t) {
            const bf16x8 bhi = *(const bf16x8*)&whi[(((ks * 4 + t) * 64) + lane) * 8];
            const bf16x8 blo = *(const bf16x8*)&wlo[(((ks * 4 + t) * 64) + lane) * 8];
            acc[t] = __builtin_amdgcn_mfma_f32_16x16x32_bf16(a, bhi, acc[t], 0, 0, 0);
            acc[t] = __builtin_amdgcn_mfma_f32_16x16x32_bf16(a, blo, acc[t], 0, 0, 0);
        }
    }

    #pragma unroll
    for (int r = 0; r < 4; ++r) {
        const int row = quad * 4 + r;
        float se = 0.f, sr = 0.f;
        #pragma unroll
        for (int t = 0; t < 4; ++t) {
            float v = acc[t][r];
            z[(size_t)(i0 + row) * HID + t * 16 + m] = bf16_rne(v);
            se = fmaf(v, al[t * 16 + m], se);
            sr = fmaf(v, ar[t * 16 + m], sr);
        }
        #pragma unroll
        for (int off = 1; off < 16; off <<= 1) {
            se += __shfl_xor(se, off, 64);
            sr += __shfl_xor(sr, off, 64);
        }
        if (m == 0) { el[i0 + row] = se; er[i0 + row] = sr; }
    }
}

// device-wide exclusive scan (2 launches; final add folded into consumers)
__global__ __launch_bounds__(256) void scan1g(
    const int* __restrict__ in, int* __restrict__ ex, int* __restrict__ bsums, int n)
{
    __shared__ int sh[256];
    const int t = threadIdx.x;
    const int i = blockIdx.x * 256 + t;
    int v = (i < n) ? in[i] : 0;
    sh[t] = v; __syncthreads();
    #pragma unroll
    for (int off = 1; off < 256; off <<= 1) {
        int x = sh[t];
        int a = (t >= off) ? sh[t - off] : 0;
        __syncthreads();
        sh[t] = x + a;
        __syncthreads();
    }
    if (i < n) ex[i] = sh[t] - v;
    if (t == 255) bsums[blockIdx.x] = sh[255];
}

__global__ __launch_bounds__(256) void scan2g(int* __restrict__ bsums, int nb)
{
    __shared__ int sh[256];
    const int t = threadIdx.x;
    int v = (t < nb) ? bsums[t] : 0;
    sh[t] = v; __syncthreads();
    #pragma unroll
    for (int off = 1; off < 256; off <<= 1) {
        int x = sh[t];
        int a = (t >= off) ? sh[t - off] : 0;
        __syncthreads();
        sh[t] = x + a;
        __syncthreads();
    }
    if (t < nb) bsums[t] = sh[t] - v;
}

// ---- MSD pass 1 scatter (global offset = local ex + bsums[idx>>8], inline) ----
__global__ __launch_bounds__(256) void scatter_hi(
    const int* __restrict__ src, const int* __restrict__ dst,
    const int* __restrict__ histEx, const int* __restrict__ bsums,
    unsigned* __restrict__ pairs)
{
    __shared__ int base[256];
    const int t = threadIdx.x, b = blockIdx.x;
    if (t < NB1) {
        int idx = t * NB1 + b;
        base[t] = histEx[idx] + bsums[idx >> 8];
    }
    __syncthreads();
    const int beg = b * CHUNK, end = min(beg + CHUNK, N_EDGES);
    for (int e = beg + t; e < end; e += 256) {
        int s = src[e], d = dst[e];
        int pos = atomicAdd(&base[d >> 8], 1);
        pairs[pos] = ((unsigned)s << 16) | (unsigned)d;   // both ids < 2^16
    }
}

// ---- MSD pass 2: one block per 256-node segment -> row_start + csr_src ----
__global__ __launch_bounds__(256) void seg_sort(
    const unsigned* __restrict__ pairs, const int* __restrict__ histEx,
    const int* __restrict__ bsums,
    int* __restrict__ row_start, int* __restrict__ csr_src)
{
    __shared__ int hist[256], sc[256], offs[256];
    const int t = threadIdx.x, b = blockIdx.x;
    const int i0 = b * NB1;
    const int segStart = histEx[i0] + bsums[i0 >> 8];
    int segEnd = N_EDGES;
    if (b < NB1 - 1) {
        const int i1 = (b + 1) * NB1;
        segEnd = histEx[i1] + bsums[i1 >> 8];
    }
    hist[t] = 0; __syncthreads();
    for (int i = segStart + t; i < segEnd; i += 256)
        atomicAdd(&hist[pairs[i] & 255], 1);
    __syncthreads();
    int v = hist[t]; sc[t] = v; __syncthreads();
    #pragma unroll
    for (int off = 1; off < 256; off <<= 1) {
        int x = sc[t];
        int a = (t >= off) ? sc[t - off] : 0;
        __syncthreads();
        sc[t] = x + a;
        __syncthreads();
    }
    const int excl = sc[t] - v;
    offs[t] = segStart + excl;
    const int node = b * 256 + t;
    if (node <= N_NODES) row_start[node] = segStart + excl;
    __syncthreads();
    for (int i = segStart + t; i < segEnd; i += 256) {
        unsigned p = pairs[i];
        int pos = atomicAdd(&offs[p & 255], 1);
        csr_src[pos] = (int)(p >> 16);
    }
}

// fused per-dst-node softmax-aggregate + relu. One wave per node.
// es = lane>>3 (edge slot 0..7), fl = lane&7 (8 bf16 feats = one uint4 per lane).
// z/h in bf16 (halved gather bytes). 2-deep pipeline (csr 2-ahead, el/z 1-ahead).
__global__ __launch_bounds__(256) void node_agg(
    const int* __restrict__ row_start, const int* __restrict__ csr_src,
    const float* __restrict__ el, const float* __restrict__ er,
    const unsigned short* __restrict__ z, unsigned short* __restrict__ h)
{
    const int lane = threadIdx.x;
    const int i = blockIdx.x * 4 + threadIdx.y;
    if (i >= N_NODES) return;
    const int rb = row_start[i], re = row_start[i + 1];
    const float er_i = er[i];
    const int es = lane >> 3;
    const int fl = lane & 7;

    float acc[8] = {0.f,0.f,0.f,0.f,0.f,0.f,0.f,0.f};
    float den = 0.f;

    int eA = rb + es;        bool vA = eA < re;
    int eB = eA + 8;         bool vB = eB < re;
    int sA = vA ? csr_src[eA] : 0;
    int sB = vB ? csr_src[eB] : 0;
    float elA = el[sA];
    uint4 zA = ((const uint4*)(z + (size_t)sA * HID))[fl];

    for (int e0 = rb; e0 < re; e0 += 8) {
        const int eC = e0 + 16 + es;
        const bool vC = eC < re;
        const int sC = vC ? csr_src[eC] : 0;                    // 2 ahead
        const float elB = el[sB];                                // 1 ahead
        const uint4 zB = ((const uint4*)(z + (size_t)sB * HID))[fl];

        float x = elA + er_i;
        float lr = x > 0.f ? x : 0.2f * x;
        float ex = vA ? __expf(lr) : 0.f;
        float z0, z1, z2, z3, z4, z5, z6, z7;
        bf2f(zA.x, z0, z1); bf2f(zA.y, z2, z3);
        bf2f(zA.z, z4, z5); bf2f(zA.w, z6, z7);
        acc[0] = fmaf(ex, z0, acc[0]); acc[1] = fmaf(ex, z1, acc[1]);
        acc[2] = fmaf(ex, z2, acc[2]); acc[3] = fmaf(ex, z3, acc[3]);
        acc[4] = fmaf(ex, z4, acc[4]); acc[5] = fmaf(ex, z5, acc[5]);
        acc[6] = fmaf(ex, z6, acc[6]); acc[7] = fmaf(ex, z7, acc[7]);
        den += ex;

        sA = sB; vA = vB; elA = elB; zA = zB;
        sB = sC; vB = vC;
    }
    // reduce across the 8 edge slots (lanes differing in bits 3,4,5)
    #pragma unroll
    for (int off = 8; off < 64; off <<= 1) {
        #pragma unroll
        for (int q = 0; q < 8; ++q) acc[q] += __shfl_xor(acc[q], off, 64);
        den += __shfl_xor(den, off, 64);
    }
    if (es == 0) {
        float inv = 1.f / fmaxf(den, 1e-9f);
        unsigned short o[8];
        #pragma unroll
        for (int q = 0; q < 8; ++q) o[q] = bf16_rne(fmaxf(acc[q] * inv, 0.f));
        uint4 pk;
        pk.x = (unsigned)o[0] | ((unsigned)o[1] << 16);
        pk.y = (unsigned)o[2] | ((unsigned)o[3] << 16);
        pk.z = (unsigned)o[4] | ((unsigned)o[5] << 16);
        pk.w = (unsigned)o[6] | ((unsigned)o[7] << 16);
        ((uint4*)(h + (size_t)i * HID))[fl] = pk;
    }
}

// 2 pairs per wave; bf16 h gathers; membership via CSR row scan.
__global__ __launch_bounds__(256) void pair_head(
    const int* __restrict__ ps, const int* __restrict__ pd,
    const unsigned short* __restrict__ h, const float* __restrict__ Wc,
    const float* __restrict__ bc, const int* __restrict__ row_start,
    const int* __restrict__ csr_src, float* __restrict__ out)
{
    const int lane = threadIdx.x;
    const int p = blockIdx.x * 8 + threadIdx.y * 2 + (lane >> 5);
    if (p >= N_PAIRS) return;
    const int r = lane & 31;
    const int which = r >> 4;
    const int f4 = r & 15;
    int s = ps[p], d = pd[p];
    int node = which ? d : s;
    const uint2 hv = ((const uint2*)(h + (size_t)node * HID))[f4];
    float h0, h1, h2, h3;
    bf2f(hv.x, h0, h1); bf2f(hv.y, h2, h3);
    const float4 wv = *(const float4*)&Wc[which * HID + f4 * 4];
    float v = h0 * wv.x + h1 * wv.y + h2 * wv.z + h3 * wv.w;

    const int rb = row_start[d], re = row_start[d + 1];
    int found = 0;
    for (int e = rb + r; e < re; e += 32) found |= (csr_src[e] == s) ? 1 : 0;

    #pragma unroll
    for (int off = 1; off < 32; off <<= 1) {
        v += __shfl_xor(v, off, 64);
        found |= __shfl_xor(found, off, 64);
    }
    if (r == 0) {
        float sg = 1.f / (1.f + __expf(-(v + bc[0])));
        out[p] = found ? sg : 0.f;
    }
}

extern "C" void kernel_launch(void* const* d_in, const int* in_sizes, int n_in,
                              void* d_out, int out_size, void* d_ws, size_t ws_size,
                              hipStream_t stream)
{
    const float* feat = (const float*)d_in[0];
    const float* W1   = (const float*)d_in[1];
    const float* al1  = (const float*)d_in[2];
    const float* ar1  = (const float*)d_in[3];
    const float* W2   = (const float*)d_in[4];
    const float* al2  = (const float*)d_in[5];
    const float* ar2  = (const float*)d_in[6];
    const float* Wc   = (const float*)d_in[7];
    const float* bc   = (const float*)d_in[8];
    const int* src    = (const int*)d_in[9];
    const int* dst    = (const int*)d_in[10];
    const int* psrc   = (const int*)d_in[11];
    const int* pdst   = (const int*)d_in[12];
    float* out = (float*)d_out;

    char* ws = (char*)d_ws;
    unsigned short* z  = (unsigned short*)ws;  ws += (size_t)N_NODES * HID * 2;
    unsigned short* h1 = (unsigned short*)ws;  ws += (size_t)N_NODES * HID * 2;
    float* el = (float*)ws;               ws += (size_t)N_NODES * 4;
    float* er = (float*)ws;               ws += (size_t)N_NODES * 4;
    int* row_start = (int*)ws;            ws += (size_t)(N_NODES + 1) * 4;
    int* histHi = (int*)ws;               ws += (size_t)MHIST * 4;
    int* bsumsA = (int*)ws;               ws += (size_t)(SBG + 1) * 4;
    ws = (char*)(((uintptr_t)ws + 255) & ~(uintptr_t)255);
    unsigned* pairs = (unsigned*)ws;      ws += (size_t)N_EDGES * 4;
    int* csr_src = (int*)ws;              ws += (size_t)N_EDGES * 4;
    unsigned short* w1hi = (unsigned short*)ws;  ws += 8192 * 2;
    unsigned short* w1lo = (unsigned short*)ws;  ws += 8192 * 2;
    unsigned short* w2hi = (unsigned short*)ws;  ws += 4096 * 2;
    unsigned short* w2lo = (unsigned short*)ws;  ws += 4096 * 2;

    dim3 b64x4(64, 4);
    const int MB = (N_WAVES_GEMM + 3) / 4;

    // ---- CSR build (MSD 2-level sort) + W fragment prep ----
    hist_prep<<<NB1 + 32, 256, 0, stream>>>(dst, histHi, W1, W2, w1hi, w1lo, w2hi, w2lo);
    scan1g<<<SBG, 256, 0, stream>>>(histHi, histHi, bsumsA, MHIST);
    scan2g<<<1, 256, 0, stream>>>(bsumsA, SBG);
    scatter_hi<<<NB1, 256, 0, stream>>>(src, dst, histHi, bsumsA, pairs);
    seg_sort<<<NB1, 256, 0, stream>>>(pairs, histHi, bsumsA, row_start, csr_src);

    // ---- layer 1 ----
    gemm_mfma_f<<<MB, b64x4, 0, stream>>>(feat, w1hi, w1lo, al1, ar1, z, el, er);
    node_agg<<<(N_NODES + 3) / 4, b64x4, 0, stream>>>(row_start, csr_src, el, er, z, h1);

    // ---- layer 2 ----
    gemm_mfma_b<<<MB, b64x4, 0, stream>>>(h1, w2hi, w2lo, al2, ar2, z, el, er);
    node_agg<<<(N_NODES + 3) / 4, b64x4, 0, stream>>>(row_start, csr_src, el, er, z, h1);

    // ---- pair head (membership via CSR row scan) ----
    pair_head<<<N_PAIRS / 8, b64x4, 0, stream>>>(psrc, pdst, h1, Wc, bc, row_start, csr_src, out);
}

// Round 13
// 193.989 us; speedup vs baseline: 4.6990x; 1.0974x over previous
//
#include <hip/hip_runtime.h>
#include <cstdint>

#define N_NODES 50000
#define N_EDGES 800000
#define N_PAIRS 200000
#define IN_DIM 128
#define HID 64
#define N_WAVES_GEMM (N_NODES / 16)           // 3125
#define NB1 196                               // high-byte bins AND edge chunks
#define CHUNK ((N_EDGES + NB1 - 1) / NB1)     // 4082
#define MHIST (NB1 * NB1)                     // 38416
#define SBG ((MHIST + 255) / 256)             // 151 scan blocks
#define MB_GEMM ((N_WAVES_GEMM + 3) / 4)      // 782
#define NODE_BLOCKS ((N_NODES + 3) / 4)       // 12500
#define MEMBER_BLOCKS (N_PAIRS / 32)          // 6250 (32 pairs/block)

typedef __attribute__((ext_vector_type(8))) short bf16x8;
typedef __attribute__((ext_vector_type(4))) float f32x4;

__device__ __forceinline__ unsigned short bf16_rne(float f) {
    unsigned u = __float_as_uint(f);
    unsigned t = u + 0x7FFFu + ((u >> 16) & 1u);
    return (unsigned short)(t >> 16);
}
__device__ __forceinline__ void bf2f(unsigned u, float& a, float& b) {
    a = __uint_as_float(u << 16);
    b = __uint_as_float(u & 0xFFFF0000u);
}

// ---- fused: MSD pass-1 histogram (blocks 0..195) + W fragment prep ----
__global__ __launch_bounds__(256) void hist_prep(
    const int* __restrict__ dst, int* __restrict__ histHi,
    const float* __restrict__ W1, const float* __restrict__ W2,
    unsigned short* __restrict__ w1hi, unsigned short* __restrict__ w1lo,
    unsigned short* __restrict__ w2hi, unsigned short* __restrict__ w2lo)
{
    const int t = threadIdx.x, b = blockIdx.x;
    if (b < NB1) {
        __shared__ int hist[256];
        hist[t] = 0; __syncthreads();
        const int beg = b * CHUNK, end = min(beg + CHUNK, N_EDGES);
        for (int e = beg + t; e < end; e += 256) atomicAdd(&hist[dst[e] >> 8], 1);
        __syncthreads();
        if (t < NB1) histHi[t * NB1 + b] = hist[t];
    } else {
        int tid = (b - NB1) * 256 + t;
        if (tid < 8192) {
            int jj = tid & 7, lane = (tid >> 3) & 63, tt = (tid >> 9) & 3, ks = tid >> 11;
            int k = ks * 32 + (lane >> 4) * 8 + jj;
            int n = tt * 16 + (lane & 15);
            float f = W1[k * HID + n];
            unsigned short hi = bf16_rne(f);
            float fhi = __uint_as_float(((unsigned)hi) << 16);
            w1hi[tid] = hi;
            w1lo[tid] = bf16_rne(f - fhi);
        }
        if (tid < 4096) {
            int jj = tid & 7, lane = (tid >> 3) & 63, tt = (tid >> 9) & 3, ks = tid >> 11;
            int k = ks * 32 + (lane >> 4) * 8 + jj;
            int n = tt * 16 + (lane & 15);
            float f = W2[k * HID + n];
            unsigned short hi = bf16_rne(f);
            float fhi = __uint_as_float(((unsigned)hi) << 16);
            w2hi[tid] = hi;
            w2lo[tid] = bf16_rne(f - fhi);
        }
    }
}

// layer-1 GEMM body: fp32 x, split-bf16 (hi*hi + hi*lo + lo*hi); z stored bf16.
__device__ __forceinline__ void gemm1_body(
    int wave, int lane,
    const float* __restrict__ x,
    const unsigned short* __restrict__ whi, const unsigned short* __restrict__ wlo,
    const float* __restrict__ al, const float* __restrict__ ar,
    unsigned short* __restrict__ z, float* __restrict__ el, float* __restrict__ er)
{
    const int i0 = wave * 16;
    const int m = lane & 15, quad = lane >> 4;
    f32x4 acc[4] = {{0.f,0.f,0.f,0.f},{0.f,0.f,0.f,0.f},{0.f,0.f,0.f,0.f},{0.f,0.f,0.f,0.f}};
    const float* xrow = x + (size_t)(i0 + m) * IN_DIM;

    #pragma unroll 1
    for (int ks = 0; ks < 4; ++ks) {
        const float4 xv0 = *(const float4*)&xrow[ks * 32 + quad * 8];
        const float4 xv1 = *(const float4*)&xrow[ks * 32 + quad * 8 + 4];
        float xs[8] = {xv0.x, xv0.y, xv0.z, xv0.w, xv1.x, xv1.y, xv1.z, xv1.w};
        bf16x8 ahi, alo;
        #pragma unroll
        for (int jj = 0; jj < 8; ++jj) {
            unsigned short hb = bf16_rne(xs[jj]);
            float fhi = __uint_as_float(((unsigned)hb) << 16);
            ahi[jj] = (short)hb;
            alo[jj] = (short)bf16_rne(xs[jj] - fhi);
        }
        #pragma unroll
        for (int t = 0; t < 4; ++t) {
            const bf16x8 bhi = *(const bf16x8*)&whi[(((ks * 4 + t) * 64) + lane) * 8];
            const bf16x8 blo = *(const bf16x8*)&wlo[(((ks * 4 + t) * 64) + lane) * 8];
            acc[t] = __builtin_amdgcn_mfma_f32_16x16x32_bf16(ahi, bhi, acc[t], 0, 0, 0);
            acc[t] = __builtin_amdgcn_mfma_f32_16x16x32_bf16(ahi, blo, acc[t], 0, 0, 0);
            acc[t] = __builtin_amdgcn_mfma_f32_16x16x32_bf16(alo, bhi, acc[t], 0, 0, 0);
        }
    }
    #pragma unroll
    for (int r = 0; r < 4; ++r) {
        const int row = quad * 4 + r;
        float se = 0.f, sr = 0.f;
        #pragma unroll
        for (int t = 0; t < 4; ++t) {
            float v = acc[t][r];
            z[(size_t)(i0 + row) * HID + t * 16 + m] = bf16_rne(v);
            se = fmaf(v, al[t * 16 + m], se);
            sr = fmaf(v, ar[t * 16 + m], sr);
        }
        #pragma unroll
        for (int off = 1; off < 16; off <<= 1) {
            se += __shfl_xor(se, off, 64);
            sr += __shfl_xor(sr, off, 64);
        }
        if (m == 0) { el[i0 + row] = se; er[i0 + row] = sr; }
    }
}

// fused: scan1 over MHIST (blocks 0..150) + layer-1 GEMM (blocks 151..932)
__global__ __launch_bounds__(256) void scan_gemm1(
    int* __restrict__ histHi, int* __restrict__ bsums,
    const float* __restrict__ x,
    const unsigned short* __restrict__ whi, const unsigned short* __restrict__ wlo,
    const float* __restrict__ al, const float* __restrict__ ar,
    unsigned short* __restrict__ z, float* __restrict__ el, float* __restrict__ er)
{
    const int b = blockIdx.x;
    if (b < SBG) {
        __shared__ int sh[256];
        const int t = threadIdx.y * 64 + threadIdx.x;
        const int i = b * 256 + t;
        int v = (i < MHIST) ? histHi[i] : 0;
        sh[t] = v; __syncthreads();
        #pragma unroll
        for (int off = 1; off < 256; off <<= 1) {
            int x2 = sh[t];
            int a = (t >= off) ? sh[t - off] : 0;
            __syncthreads();
            sh[t] = x2 + a;
            __syncthreads();
        }
        if (i < MHIST) histHi[i] = sh[t] - v;
        if (t == 255) bsums[b] = sh[255];
    } else {
        const int wave = (b - SBG) * 4 + threadIdx.y;
        if (wave < N_WAVES_GEMM)
            gemm1_body(wave, threadIdx.x, x, whi, wlo, al, ar, z, el, er);
    }
}

// in-block exclusive scan of the 151 bsums partials -> exb[]
__device__ __forceinline__ void scan_bsums(const int* __restrict__ bsums,
                                           int* sh, int* exb, int t)
{
    int v = (t < SBG) ? bsums[t] : 0;
    sh[t] = v; __syncthreads();
    #pragma unroll
    for (int off = 1; off < 256; off <<= 1) {
        int x = sh[t];
        int a = (t >= off) ? sh[t - off] : 0;
        __syncthreads();
        sh[t] = x + a;
        __syncthreads();
    }
    exb[t] = sh[t] - v;
    __syncthreads();
}

// ---- MSD pass 1 scatter ----
__global__ __launch_bounds__(256) void scatter_hi(
    const int* __restrict__ src, const int* __restrict__ dst,
    const int* __restrict__ histEx, const int* __restrict__ bsums,
    unsigned* __restrict__ pairs)
{
    __shared__ int sh[256], exb[256], base[256];
    const int t = threadIdx.x, b = blockIdx.x;
    scan_bsums(bsums, sh, exb, t);
    if (t < NB1) {
        int idx = t * NB1 + b;
        base[t] = histEx[idx] + exb[idx >> 8];
    }
    __syncthreads();
    const int beg = b * CHUNK, end = min(beg + CHUNK, N_EDGES);
    for (int e = beg + t; e < end; e += 256) {
        int s = src[e], d = dst[e];
        int pos = atomicAdd(&base[d >> 8], 1);
        pairs[pos] = ((unsigned)s << 16) | (unsigned)d;   // both ids < 2^16
    }
}

// ---- MSD pass 2: one block per 256-node segment -> row_start + csr_src ----
__global__ __launch_bounds__(256) void seg_sort(
    const unsigned* __restrict__ pairs, const int* __restrict__ histEx,
    const int* __restrict__ bsums,
    int* __restrict__ row_start, int* __restrict__ csr_src)
{
    __shared__ int sh[256], exb[256], hist[256], sc[256], offs[256];
    const int t = threadIdx.x, b = blockIdx.x;
    scan_bsums(bsums, sh, exb, t);
    const int i0 = b * NB1;
    const int segStart = histEx[i0] + exb[i0 >> 8];
    int segEnd = N_EDGES;
    if (b < NB1 - 1) {
        const int i1 = (b + 1) * NB1;
        segEnd = histEx[i1] + exb[i1 >> 8];
    }
    hist[t] = 0; __syncthreads();
    for (int i = segStart + t; i < segEnd; i += 256)
        atomicAdd(&hist[pairs[i] & 255], 1);
    __syncthreads();
    int v = hist[t]; sc[t] = v; __syncthreads();
    #pragma unroll
    for (int off = 1; off < 256; off <<= 1) {
        int x = sc[t];
        int a = (t >= off) ? sc[t - off] : 0;
        __syncthreads();
        sc[t] = x + a;
        __syncthreads();
    }
    const int excl = sc[t] - v;
    offs[t] = segStart + excl;
    const int node = b * 256 + t;
    if (node <= N_NODES) row_start[node] = segStart + excl;
    __syncthreads();
    for (int i = segStart + t; i < segEnd; i += 256) {
        unsigned p = pairs[i];
        int pos = atomicAdd(&offs[p & 255], 1);
        csr_src[pos] = (int)(p >> 16);
    }
}

// per-dst-node softmax-aggregate + relu body. One wave per node.
// LAST=false: writes bf16 h row. LAST=true: writes head dots a_s,a_d only.
template <bool LAST>
__device__ __forceinline__ void agg_body(
    int i, int lane,
    const int* __restrict__ row_start, const int* __restrict__ csr_src,
    const float* __restrict__ el, const float* __restrict__ er,
    const unsigned short* __restrict__ z, unsigned short* __restrict__ h,
    const float* __restrict__ Wc, float* __restrict__ as, float* __restrict__ ad)
{
    const int rb = row_start[i], re = row_start[i + 1];
    const float er_i = er[i];
    const int es = lane >> 3;
    const int fl = lane & 7;

    float acc[8] = {0.f,0.f,0.f,0.f,0.f,0.f,0.f,0.f};
    float den = 0.f;

    int eA = rb + es;        bool vA = eA < re;
    int eB = eA + 8;         bool vB = eB < re;
    int sA = vA ? csr_src[eA] : 0;
    int sB = vB ? csr_src[eB] : 0;
    float elA = el[sA];
    uint4 zA = ((const uint4*)(z + (size_t)sA * HID))[fl];

    for (int e0 = rb; e0 < re; e0 += 8) {
        const int eC = e0 + 16 + es;
        const bool vC = eC < re;
        const int sC = vC ? csr_src[eC] : 0;                    // 2 ahead
        const float elB = el[sB];                                // 1 ahead
        const uint4 zB = ((const uint4*)(z + (size_t)sB * HID))[fl];

        float x = elA + er_i;
        float lr = x > 0.f ? x : 0.2f * x;
        float ex = vA ? __expf(lr) : 0.f;
        float z0, z1, z2, z3, z4, z5, z6, z7;
        bf2f(zA.x, z0, z1); bf2f(zA.y, z2, z3);
        bf2f(zA.z, z4, z5); bf2f(zA.w, z6, z7);
        acc[0] = fmaf(ex, z0, acc[0]); acc[1] = fmaf(ex, z1, acc[1]);
        acc[2] = fmaf(ex, z2, acc[2]); acc[3] = fmaf(ex, z3, acc[3]);
        acc[4] = fmaf(ex, z4, acc[4]); acc[5] = fmaf(ex, z5, acc[5]);
        acc[6] = fmaf(ex, z6, acc[6]); acc[7] = fmaf(ex, z7, acc[7]);
        den += ex;

        sA = sB; vA = vB; elA = elB; zA = zB;
        sB = sC; vB = vC;
    }
    #pragma unroll
    for (int off = 8; off < 64; off <<= 1) {
        #pragma unroll
        for (int q = 0; q < 8; ++q) acc[q] += __shfl_xor(acc[q], off, 64);
        den += __shfl_xor(den, off, 64);
    }
    if (es == 0) {
        float inv = 1.f / fmaxf(den, 1e-9f);
        float hv[8];
        #pragma unroll
        for (int q = 0; q < 8; ++q) hv[q] = fmaxf(acc[q] * inv, 0.f);
        if (LAST) {
            // head dots: a_s = h . Wc[0:64], a_d = h . Wc[64:128]
            float ps = 0.f, pd = 0.f;
            #pragma unroll
            for (int q = 0; q < 8; ++q) {
                ps = fmaf(hv[q], Wc[fl * 8 + q], ps);
                pd = fmaf(hv[q], Wc[HID + fl * 8 + q], pd);
            }
            #pragma unroll
            for (int off = 1; off < 8; off <<= 1) {
                ps += __shfl_xor(ps, off, 64);
                pd += __shfl_xor(pd, off, 64);
            }
            if (fl == 0) { as[i] = ps; ad[i] = pd; }
        } else {
            unsigned short o[8];
            #pragma unroll
            for (int q = 0; q < 8; ++q) o[q] = bf16_rne(hv[q]);
            uint4 pk;
            pk.x = (unsigned)o[0] | ((unsigned)o[1] << 16);
            pk.y = (unsigned)o[2] | ((unsigned)o[3] << 16);
            pk.z = (unsigned)o[4] | ((unsigned)o[5] << 16);
            pk.w = (unsigned)o[6] | ((unsigned)o[7] << 16);
            ((uint4*)(h + (size_t)i * HID))[fl] = pk;
        }
    }
}

// fused: layer-1 aggregate (blocks 0..12499) + pair membership (12500..18749).
// membership: 8 lanes per pair scan the dst's CSR row.
__global__ __launch_bounds__(256) void agg1_member(
    const int* __restrict__ row_start, const int* __restrict__ csr_src,
    const float* __restrict__ el, const float* __restrict__ er,
    const unsigned short* __restrict__ z, unsigned short* __restrict__ h,
    const int* __restrict__ ps, const int* __restrict__ pd,
    int* __restrict__ found)
{
    const int lane = threadIdx.x, b = blockIdx.x;
    if (b < NODE_BLOCKS) {
        const int i = b * 4 + threadIdx.y;
        if (i < N_NODES)
            agg_body<false>(i, lane, row_start, csr_src, el, er, z, h,
                            nullptr, nullptr, nullptr);
    } else {
        const int r = lane & 7, g = lane >> 3;
        const int p = (b - NODE_BLOCKS) * 32 + threadIdx.y * 8 + g;
        const int s = ps[p], d = pd[p];
        const int rb = row_start[d], re = row_start[d + 1];
        int f = 0;
        for (int e = rb + r; e < re; e += 8) f |= (csr_src[e] == s) ? 1 : 0;
        #pragma unroll
        for (int off = 1; off < 8; off <<= 1) f |= __shfl_xor(f, off, 64);
        if (r == 0) found[p] = f;
    }
}

// layer-2 GEMM: bf16 h input, 2 MFMAs/tile.
__global__ __launch_bounds__(256) void gemm_mfma_b(
    const unsigned short* __restrict__ x,
    const unsigned short* __restrict__ whi, const unsigned short* __restrict__ wlo,
    const float* __restrict__ al, const float* __restrict__ ar,
    unsigned short* __restrict__ z, float* __restrict__ el, float* __restrict__ er)
{
    const int lane = threadIdx.x;
    const int wave = blockIdx.x * 4 + threadIdx.y;
    if (wave >= N_WAVES_GEMM) return;
    const int i0 = wave * 16;
    const int m = lane & 15, quad = lane >> 4;

    f32x4 acc[4] = {{0.f,0.f,0.f,0.f},{0.f,0.f,0.f,0.f},{0.f,0.f,0.f,0.f},{0.f,0.f,0.f,0.f}};
    const unsigned short* xrow = x + (size_t)(i0 + m) * HID;

    #pragma unroll 1
    for (int ks = 0; ks < 2; ++ks) {
        const bf16x8 a = *(const bf16x8*)&xrow[ks * 32 + quad * 8];
        #pragma unroll
        for (int t = 0; t < 4; ++t) {
            const bf16x8 bhi = *(const bf16x8*)&whi[(((ks * 4 + t) * 64) + lane) * 8];
            const bf16x8 blo = *(const bf16x8*)&wlo[(((ks * 4 + t) * 64) + lane) * 8];
            acc[t] = __builtin_amdgcn_mfma_f32_16x16x32_bf16(a, bhi, acc[t], 0, 0, 0);
            acc[t] = __builtin_amdgcn_mfma_f32_16x16x32_bf16(a, blo, acc[t], 0, 0, 0);
        }
    }
    #pragma unroll
    for (int r = 0; r < 4; ++r) {
        const int row = quad * 4 + r;
        float se = 0.f, sr = 0.f;
        #pragma unroll
        for (int t = 0; t < 4; ++t) {
            float v = acc[t][r];
            z[(size_t)(i0 + row) * HID + t * 16 + m] = bf16_rne(v);
            se = fmaf(v, al[t * 16 + m], se);
            sr = fmaf(v, ar[t * 16 + m], sr);
        }
        #pragma unroll
        for (int off = 1; off < 16; off <<= 1) {
            se += __shfl_xor(se, off, 64);
            sr += __shfl_xor(sr, off, 64);
        }
        if (m == 0) { el[i0 + row] = se; er[i0 + row] = sr; }
    }
}

// layer-2 aggregate: writes a_s/a_d head dots only (no h).
__global__ __launch_bounds__(256) void agg2(
    const int* __restrict__ row_start, const int* __restrict__ csr_src,
    const float* __restrict__ el, const float* __restrict__ er,
    const unsigned short* __restrict__ z, const float* __restrict__ Wc,
    float* __restrict__ as, float* __restrict__ ad)
{
    const int i = blockIdx.x * 4 + threadIdx.y;
    if (i < N_NODES)
        agg_body<true>(i, threadIdx.x, row_start, csr_src, el, er, z,
                       nullptr, Wc, as, ad);
}

// final: out[p] = found ? sigmoid(a_s[s] + a_d[d] + bc) : 0
__global__ __launch_bounds__(256) void pair_tiny(
    const int* __restrict__ ps, const int* __restrict__ pd,
    const float* __restrict__ as, const float* __restrict__ ad,
    const float* __restrict__ bc, const int* __restrict__ found,
    float* __restrict__ out)
{
    const int p = blockIdx.x * 256 + threadIdx.x;
    if (p >= N_PAIRS) return;
    float v = as[ps[p]] + ad[pd[p]] + bc[0];
    float sg = 1.f / (1.f + __expf(-v));
    out[p] = found[p] ? sg : 0.f;
}

extern "C" void kernel_launch(void* const* d_in, const int* in_sizes, int n_in,
                              void* d_out, int out_size, void* d_ws, size_t ws_size,
                              hipStream_t stream)
{
    const float* feat = (const float*)d_in[0];
    const float* W1   = (const float*)d_in[1];
    const float* al1  = (const float*)d_in[2];
    const float* ar1  = (const float*)d_in[3];
    const float* W2   = (const float*)d_in[4];
    const float* al2  = (const float*)d_in[5];
    const float* ar2  = (const float*)d_in[6];
    const float* Wc   = (const float*)d_in[7];
    const float* bc   = (const float*)d_in[8];
    const int* src    = (const int*)d_in[9];
    const int* dst    = (const int*)d_in[10];
    const int* psrc   = (const int*)d_in[11];
    const int* pdst   = (const int*)d_in[12];
    float* out = (float*)d_out;

    char* ws = (char*)d_ws;
    unsigned short* z  = (unsigned short*)ws;  ws += (size_t)N_NODES * HID * 2;
    unsigned short* h1 = (unsigned short*)ws;  ws += (size_t)N_NODES * HID * 2;
    float* el = (float*)ws;               ws += (size_t)N_NODES * 4;
    float* er = (float*)ws;               ws += (size_t)N_NODES * 4;
    float* as = (float*)ws;               ws += (size_t)N_NODES * 4;
    float* ad = (float*)ws;               ws += (size_t)N_NODES * 4;
    int* row_start = (int*)ws;            ws += (size_t)(N_NODES + 1) * 4;
    int* histHi = (int*)ws;               ws += (size_t)MHIST * 4;
    int* bsumsA = (int*)ws;               ws += (size_t)(SBG + 1) * 4;
    int* found = (int*)ws;                ws += (size_t)N_PAIRS * 4;
    ws = (char*)(((uintptr_t)ws + 255) & ~(uintptr_t)255);
    unsigned* pairs = (unsigned*)ws;      ws += (size_t)N_EDGES * 4;
    int* csr_src = (int*)ws;              ws += (size_t)N_EDGES * 4;
    unsigned short* w1hi = (unsigned short*)ws;  ws += 8192 * 2;
    unsigned short* w1lo = (unsigned short*)ws;  ws += 8192 * 2;
    unsigned short* w2hi = (unsigned short*)ws;  ws += 4096 * 2;
    unsigned short* w2lo = (unsigned short*)ws;  ws += 4096 * 2;

    dim3 b64x4(64, 4);

    // 1) histogram + W prep
    hist_prep<<<NB1 + 32, 256, 0, stream>>>(dst, histHi, W1, W2, w1hi, w1lo, w2hi, w2lo);
    // 2) scan1 over MHIST || layer-1 GEMM (independent, fused launch)
    scan_gemm1<<<SBG + MB_GEMM, b64x4, 0, stream>>>(histHi, bsumsA,
        feat, w1hi, w1lo, al1, ar1, z, el, er);
    // 3) bucket scatter (in-block bsums scan)
    scatter_hi<<<NB1, 256, 0, stream>>>(src, dst, histHi, bsumsA, pairs);
    // 4) segment sort -> row_start + csr_src
    seg_sort<<<NB1, 256, 0, stream>>>(pairs, histHi, bsumsA, row_start, csr_src);
    // 5) layer-1 aggregate || pair membership (fused launch)
    agg1_member<<<NODE_BLOCKS + MEMBER_BLOCKS, b64x4, 0, stream>>>(
        row_start, csr_src, el, er, z, h1, psrc, pdst, found);
    // 6) layer-2 GEMM
    gemm_mfma_b<<<MB_GEMM, b64x4, 0, stream>>>(h1, w2hi, w2lo, al2, ar2, z, el, er);
    // 7) layer-2 aggregate + head dots
    agg2<<<NODE_BLOCKS, b64x4, 0, stream>>>(row_start, csr_src, el, er, z, Wc, as, ad);
    // 8) final pair output
    pair_tiny<<<(N_PAIRS + 255) / 256, 256, 0, stream>>>(psrc, pdst, as, ad, bc, found, out);
}

// Round 14
// 192.671 us; speedup vs baseline: 4.7311x; 1.0068x over previous
//
#include <hip/hip_runtime.h>
#include <cstdint>

#define N_NODES 50000
#define N_EDGES 800000
#define N_PAIRS 200000
#define IN_DIM 128
#define HID 64
#define N_WAVES_GEMM (N_NODES / 16)           // 3125
#define NB1 196                               // high-byte bins AND edge chunks
#define CHUNK ((N_EDGES + NB1 - 1) / NB1)     // 4082
#define MHIST (NB1 * NB1)                     // 38416
#define SBG ((MHIST + 255) / 256)             // 151 scan blocks
#define MB_GEMM ((N_WAVES_GEMM + 3) / 4)      // 782
#define NODE_BLOCKS ((N_NODES + 3) / 4)       // 12500
#define MEMBER_BLOCKS (N_PAIRS / 32)          // 6250 (32 pairs/block)

typedef __attribute__((ext_vector_type(8))) short bf16x8;
typedef __attribute__((ext_vector_type(4))) float f32x4;

__device__ __forceinline__ unsigned short bf16_rne(float f) {
    unsigned u = __float_as_uint(f);
    unsigned t = u + 0x7FFFu + ((u >> 16) & 1u);
    return (unsigned short)(t >> 16);
}
__device__ __forceinline__ void bf2f(unsigned u, float& a, float& b) {
    a = __uint_as_float(u << 16);
    b = __uint_as_float(u & 0xFFFF0000u);
}

// ---- fused: MSD pass-1 histogram (blocks 0..195) + W fragment prep ----
__global__ __launch_bounds__(256) void hist_prep(
    const int* __restrict__ dst, int* __restrict__ histHi,
    const float* __restrict__ W1, const float* __restrict__ W2,
    unsigned short* __restrict__ w1hi, unsigned short* __restrict__ w1lo,
    unsigned short* __restrict__ w2hi, unsigned short* __restrict__ w2lo)
{
    const int t = threadIdx.x, b = blockIdx.x;
    if (b < NB1) {
        __shared__ int hist[256];
        hist[t] = 0; __syncthreads();
        const int beg = b * CHUNK, end = min(beg + CHUNK, N_EDGES);
        for (int e = beg + t; e < end; e += 256) atomicAdd(&hist[dst[e] >> 8], 1);
        __syncthreads();
        if (t < NB1) histHi[t * NB1 + b] = hist[t];
    } else {
        int tid = (b - NB1) * 256 + t;
        if (tid < 8192) {
            int jj = tid & 7, lane = (tid >> 3) & 63, tt = (tid >> 9) & 3, ks = tid >> 11;
            int k = ks * 32 + (lane >> 4) * 8 + jj;
            int n = tt * 16 + (lane & 15);
            float f = W1[k * HID + n];
            unsigned short hi = bf16_rne(f);
            float fhi = __uint_as_float(((unsigned)hi) << 16);
            w1hi[tid] = hi;
            w1lo[tid] = bf16_rne(f - fhi);
        }
        if (tid < 4096) {
            int jj = tid & 7, lane = (tid >> 3) & 63, tt = (tid >> 9) & 3, ks = tid >> 11;
            int k = ks * 32 + (lane >> 4) * 8 + jj;
            int n = tt * 16 + (lane & 15);
            float f = W2[k * HID + n];
            unsigned short hi = bf16_rne(f);
            float fhi = __uint_as_float(((unsigned)hi) << 16);
            w2hi[tid] = hi;
            w2lo[tid] = bf16_rne(f - fhi);
        }
    }
}

// device-wide scan step 1 (standalone, tiny)
__global__ __launch_bounds__(256) void scan1g(
    int* __restrict__ histHi, int* __restrict__ bsums)
{
    __shared__ int sh[256];
    const int t = threadIdx.x;
    const int i = blockIdx.x * 256 + t;
    int v = (i < MHIST) ? histHi[i] : 0;
    sh[t] = v; __syncthreads();
    #pragma unroll
    for (int off = 1; off < 256; off <<= 1) {
        int x = sh[t];
        int a = (t >= off) ? sh[t - off] : 0;
        __syncthreads();
        sh[t] = x + a;
        __syncthreads();
    }
    if (i < MHIST) histHi[i] = sh[t] - v;
    if (t == 255) bsums[blockIdx.x] = sh[255];
}

// in-block exclusive scan of the 151 bsums partials -> exb[]
__device__ __forceinline__ void scan_bsums(const int* __restrict__ bsums,
                                           int* sh, int* exb, int t)
{
    int v = (t < SBG) ? bsums[t] : 0;
    sh[t] = v; __syncthreads();
    #pragma unroll
    for (int off = 1; off < 256; off <<= 1) {
        int x = sh[t];
        int a = (t >= off) ? sh[t - off] : 0;
        __syncthreads();
        sh[t] = x + a;
        __syncthreads();
    }
    exb[t] = sh[t] - v;
    __syncthreads();
}

// layer-1 GEMM body: fp32 x, split-bf16 (hi*hi + hi*lo + lo*hi); z stored bf16.
__device__ __forceinline__ void gemm1_body(
    int wave, int lane,
    const float* __restrict__ x,
    const unsigned short* __restrict__ whi, const unsigned short* __restrict__ wlo,
    const float* __restrict__ al, const float* __restrict__ ar,
    unsigned short* __restrict__ z, float* __restrict__ el, float* __restrict__ er)
{
    const int i0 = wave * 16;
    const int m = lane & 15, quad = lane >> 4;
    f32x4 acc[4] = {{0.f,0.f,0.f,0.f},{0.f,0.f,0.f,0.f},{0.f,0.f,0.f,0.f},{0.f,0.f,0.f,0.f}};
    const float* xrow = x + (size_t)(i0 + m) * IN_DIM;

    #pragma unroll 1
    for (int ks = 0; ks < 4; ++ks) {
        const float4 xv0 = *(const float4*)&xrow[ks * 32 + quad * 8];
        const float4 xv1 = *(const float4*)&xrow[ks * 32 + quad * 8 + 4];
        float xs[8] = {xv0.x, xv0.y, xv0.z, xv0.w, xv1.x, xv1.y, xv1.z, xv1.w};
        bf16x8 ahi, alo;
        #pragma unroll
        for (int jj = 0; jj < 8; ++jj) {
            unsigned short hb = bf16_rne(xs[jj]);
            float fhi = __uint_as_float(((unsigned)hb) << 16);
            ahi[jj] = (short)hb;
            alo[jj] = (short)bf16_rne(xs[jj] - fhi);
        }
        #pragma unroll
        for (int t = 0; t < 4; ++t) {
            const bf16x8 bhi = *(const bf16x8*)&whi[(((ks * 4 + t) * 64) + lane) * 8];
            const bf16x8 blo = *(const bf16x8*)&wlo[(((ks * 4 + t) * 64) + lane) * 8];
            acc[t] = __builtin_amdgcn_mfma_f32_16x16x32_bf16(ahi, bhi, acc[t], 0, 0, 0);
            acc[t] = __builtin_amdgcn_mfma_f32_16x16x32_bf16(ahi, blo, acc[t], 0, 0, 0);
            acc[t] = __builtin_amdgcn_mfma_f32_16x16x32_bf16(alo, bhi, acc[t], 0, 0, 0);
        }
    }
    #pragma unroll
    for (int r = 0; r < 4; ++r) {
        const int row = quad * 4 + r;
        float se = 0.f, sr = 0.f;
        #pragma unroll
        for (int t = 0; t < 4; ++t) {
            float v = acc[t][r];
            z[(size_t)(i0 + row) * HID + t * 16 + m] = bf16_rne(v);
            se = fmaf(v, al[t * 16 + m], se);
            sr = fmaf(v, ar[t * 16 + m], sr);
        }
        #pragma unroll
        for (int off = 1; off < 16; off <<= 1) {
            se += __shfl_xor(se, off, 64);
            sr += __shfl_xor(sr, off, 64);
        }
        if (m == 0) { el[i0 + row] = se; er[i0 + row] = sr; }
    }
}

// fused: MSD pass-1 scatter (blocks 0..195) + layer-1 GEMM (blocks 196..).
// Both depend only on hist_prep + scan1 -> gemm1 hides behind the scatter.
__global__ __launch_bounds__(256) void scatter_gemm1(
    const int* __restrict__ src, const int* __restrict__ dst,
    const int* __restrict__ histEx, const int* __restrict__ bsums,
    unsigned* __restrict__ pairs,
    const float* __restrict__ x,
    const unsigned short* __restrict__ whi, const unsigned short* __restrict__ wlo,
    const float* __restrict__ al, const float* __restrict__ ar,
    unsigned short* __restrict__ z, float* __restrict__ el, float* __restrict__ er)
{
    const int b = blockIdx.x;
    if (b < NB1) {
        __shared__ int sh[256], exb[256], base[256];
        const int t = threadIdx.y * 64 + threadIdx.x;
        scan_bsums(bsums, sh, exb, t);
        if (t < NB1) {
            int idx = t * NB1 + b;
            base[t] = histEx[idx] + exb[idx >> 8];
        }
        __syncthreads();
        const int beg = b * CHUNK, end = min(beg + CHUNK, N_EDGES);
        for (int e = beg + t; e < end; e += 256) {
            int s = src[e], d = dst[e];
            int pos = atomicAdd(&base[d >> 8], 1);
            pairs[pos] = ((unsigned)s << 16) | (unsigned)d;   // both ids < 2^16
        }
    } else {
        const int wave = (b - NB1) * 4 + threadIdx.y;
        if (wave < N_WAVES_GEMM)
            gemm1_body(wave, threadIdx.x, x, whi, wlo, al, ar, z, el, er);
    }
}

// ---- MSD pass 2: one block per 256-node segment -> row_start + csr_src (u16) ----
__global__ __launch_bounds__(256) void seg_sort(
    const unsigned* __restrict__ pairs, const int* __restrict__ histEx,
    const int* __restrict__ bsums,
    int* __restrict__ row_start, unsigned short* __restrict__ csr_src)
{
    __shared__ int sh[256], exb[256], hist[256], sc[256], offs[256];
    const int t = threadIdx.x, b = blockIdx.x;
    scan_bsums(bsums, sh, exb, t);
    const int i0 = b * NB1;
    const int segStart = histEx[i0] + exb[i0 >> 8];
    int segEnd = N_EDGES;
    if (b < NB1 - 1) {
        const int i1 = (b + 1) * NB1;
        segEnd = histEx[i1] + exb[i1 >> 8];
    }
    hist[t] = 0; __syncthreads();
    for (int i = segStart + t; i < segEnd; i += 256)
        atomicAdd(&hist[pairs[i] & 255], 1);
    __syncthreads();
    int v = hist[t]; sc[t] = v; __syncthreads();
    #pragma unroll
    for (int off = 1; off < 256; off <<= 1) {
        int x = sc[t];
        int a = (t >= off) ? sc[t - off] : 0;
        __syncthreads();
        sc[t] = x + a;
        __syncthreads();
    }
    const int excl = sc[t] - v;
    offs[t] = segStart + excl;
    const int node = b * 256 + t;
    if (node <= N_NODES) row_start[node] = segStart + excl;
    __syncthreads();
    for (int i = segStart + t; i < segEnd; i += 256) {
        unsigned p = pairs[i];
        int pos = atomicAdd(&offs[p & 255], 1);
        csr_src[pos] = (unsigned short)(p >> 16);
    }
}

// per-dst-node softmax-aggregate + relu body. One wave per node.
// LAST=false: writes bf16 h row. LAST=true: writes head dots a_s,a_d only.
template <bool LAST>
__device__ __forceinline__ void agg_body(
    int i, int lane,
    const int* __restrict__ row_start, const unsigned short* __restrict__ csr_src,
    const float* __restrict__ el, const float* __restrict__ er,
    const unsigned short* __restrict__ z, unsigned short* __restrict__ h,
    const float* __restrict__ Wc, float* __restrict__ as, float* __restrict__ ad)
{
    const int rb = row_start[i], re = row_start[i + 1];
    const float er_i = er[i];
    const int es = lane >> 3;
    const int fl = lane & 7;

    float acc[8] = {0.f,0.f,0.f,0.f,0.f,0.f,0.f,0.f};
    float den = 0.f;

    int eA = rb + es;        bool vA = eA < re;
    int eB = eA + 8;         bool vB = eB < re;
    int sA = vA ? (int)csr_src[eA] : 0;
    int sB = vB ? (int)csr_src[eB] : 0;
    float elA = el[sA];
    uint4 zA = ((const uint4*)(z + (size_t)sA * HID))[fl];

    for (int e0 = rb; e0 < re; e0 += 8) {
        const int eC = e0 + 16 + es;
        const bool vC = eC < re;
        const int sC = vC ? (int)csr_src[eC] : 0;               // 2 ahead
        const float elB = el[sB];                                // 1 ahead
        const uint4 zB = ((const uint4*)(z + (size_t)sB * HID))[fl];

        float x = elA + er_i;
        float lr = x > 0.f ? x : 0.2f * x;
        float ex = vA ? __expf(lr) : 0.f;
        float z0, z1, z2, z3, z4, z5, z6, z7;
        bf2f(zA.x, z0, z1); bf2f(zA.y, z2, z3);
        bf2f(zA.z, z4, z5); bf2f(zA.w, z6, z7);
        acc[0] = fmaf(ex, z0, acc[0]); acc[1] = fmaf(ex, z1, acc[1]);
        acc[2] = fmaf(ex, z2, acc[2]); acc[3] = fmaf(ex, z3, acc[3]);
        acc[4] = fmaf(ex, z4, acc[4]); acc[5] = fmaf(ex, z5, acc[5]);
        acc[6] = fmaf(ex, z6, acc[6]); acc[7] = fmaf(ex, z7, acc[7]);
        den += ex;

        sA = sB; vA = vB; elA = elB; zA = zB;
        sB = sC; vB = vC;
    }
    #pragma unroll
    for (int off = 8; off < 64; off <<= 1) {
        #pragma unroll
        for (int q = 0; q < 8; ++q) acc[q] += __shfl_xor(acc[q], off, 64);
        den += __shfl_xor(den, off, 64);
    }
    if (es == 0) {
        float inv = 1.f / fmaxf(den, 1e-9f);
        float hv[8];
        #pragma unroll
        for (int q = 0; q < 8; ++q) hv[q] = fmaxf(acc[q] * inv, 0.f);
        if (LAST) {
            float ps = 0.f, pd = 0.f;
            #pragma unroll
            for (int q = 0; q < 8; ++q) {
                ps = fmaf(hv[q], Wc[fl * 8 + q], ps);
                pd = fmaf(hv[q], Wc[HID + fl * 8 + q], pd);
            }
            #pragma unroll
            for (int off = 1; off < 8; off <<= 1) {
                ps += __shfl_xor(ps, off, 64);
                pd += __shfl_xor(pd, off, 64);
            }
            if (fl == 0) { as[i] = ps; ad[i] = pd; }
        } else {
            unsigned short o[8];
            #pragma unroll
            for (int q = 0; q < 8; ++q) o[q] = bf16_rne(hv[q]);
            uint4 pk;
            pk.x = (unsigned)o[0] | ((unsigned)o[1] << 16);
            pk.y = (unsigned)o[2] | ((unsigned)o[3] << 16);
            pk.z = (unsigned)o[4] | ((unsigned)o[5] << 16);
            pk.w = (unsigned)o[6] | ((unsigned)o[7] << 16);
            ((uint4*)(h + (size_t)i * HID))[fl] = pk;
        }
    }
}

// layer-1 aggregate (standalone)
__global__ __launch_bounds__(256) void agg1(
    const int* __restrict__ row_start, const unsigned short* __restrict__ csr_src,
    const float* __restrict__ el, const float* __restrict__ er,
    const unsigned short* __restrict__ z, unsigned short* __restrict__ h)
{
    const int i = blockIdx.x * 4 + threadIdx.y;
    if (i < N_NODES)
        agg_body<false>(i, threadIdx.x, row_start, csr_src, el, er, z, h,
                        nullptr, nullptr, nullptr);
}

// fused: layer-2 GEMM (blocks 0..781) + pair membership (782..7031).
// gemm_b is only 782 blocks -> membership fills the idle CUs.
__global__ __launch_bounds__(256) void gemm2_member(
    const unsigned short* __restrict__ x,
    const unsigned short* __restrict__ whi, const unsigned short* __restrict__ wlo,
    const float* __restrict__ al, const float* __restrict__ ar,
    unsigned short* __restrict__ z, float* __restrict__ el, float* __restrict__ er,
    const int* __restrict__ row_start, const unsigned short* __restrict__ csr_src,
    const int* __restrict__ ps, const int* __restrict__ pd, int* __restrict__ found)
{
    const int lane = threadIdx.x, b = blockIdx.x;
    if (b < MB_GEMM) {
        const int wave = b * 4 + threadIdx.y;
        if (wave >= N_WAVES_GEMM) return;
        const int i0 = wave * 16;
        const int m = lane & 15, quad = lane >> 4;
        f32x4 acc[4] = {{0.f,0.f,0.f,0.f},{0.f,0.f,0.f,0.f},{0.f,0.f,0.f,0.f},{0.f,0.f,0.f,0.f}};
        const unsigned short* xrow = x + (size_t)(i0 + m) * HID;
        #pragma unroll 1
        for (int ks = 0; ks < 2; ++ks) {
            const bf16x8 a = *(const bf16x8*)&xrow[ks * 32 + quad * 8];
            #pragma unroll
            for (int t = 0; t < 4; ++t) {
                const bf16x8 bhi = *(const bf16x8*)&whi[(((ks * 4 + t) * 64) + lane) * 8];
                const bf16x8 blo = *(const bf16x8*)&wlo[(((ks * 4 + t) * 64) + lane) * 8];
                acc[t] = __builtin_amdgcn_mfma_f32_16x16x32_bf16(a, bhi, acc[t], 0, 0, 0);
                acc[t] = __builtin_amdgcn_mfma_f32_16x16x32_bf16(a, blo, acc[t], 0, 0, 0);
            }
        }
        #pragma unroll
        for (int r = 0; r < 4; ++r) {
            const int row = quad * 4 + r;
            float se = 0.f, sr = 0.f;
            #pragma unroll
            for (int t = 0; t < 4; ++t) {
                float v = acc[t][r];
                z[(size_t)(i0 + row) * HID + t * 16 + m] = bf16_rne(v);
                se = fmaf(v, al[t * 16 + m], se);
                sr = fmaf(v, ar[t * 16 + m], sr);
            }
            #pragma unroll
            for (int off = 1; off < 16; off <<= 1) {
                se += __shfl_xor(se, off, 64);
                sr += __shfl_xor(sr, off, 64);
            }
            if (m == 0) { el[i0 + row] = se; er[i0 + row] = sr; }
        }
    } else {
        const int r = lane & 7, g = lane >> 3;
        const int p = (b - MB_GEMM) * 32 + threadIdx.y * 8 + g;
        const int s = ps[p], d = pd[p];
        const int rb = row_start[d], re = row_start[d + 1];
        int f = 0;
        for (int e = rb + r; e < re; e += 8) f |= ((int)csr_src[e] == s) ? 1 : 0;
        #pragma unroll
        for (int off = 1; off < 8; off <<= 1) f |= __shfl_xor(f, off, 64);
        if (r == 0) found[p] = f;
    }
}

// layer-2 aggregate: writes a_s/a_d head dots only (no h).
__global__ __launch_bounds__(256) void agg2(
    const int* __restrict__ row_start, const unsigned short* __restrict__ csr_src,
    const float* __restrict__ el, const float* __restrict__ er,
    const unsigned short* __restrict__ z, const float* __restrict__ Wc,
    float* __restrict__ as, float* __restrict__ ad)
{
    const int i = blockIdx.x * 4 + threadIdx.y;
    if (i < N_NODES)
        agg_body<true>(i, threadIdx.x, row_start, csr_src, el, er, z,
                       nullptr, Wc, as, ad);
}

// final: out[p] = found ? sigmoid(a_s[s] + a_d[d] + bc) : 0
__global__ __launch_bounds__(256) void pair_tiny(
    const int* __restrict__ ps, const int* __restrict__ pd,
    const float* __restrict__ as, const float* __restrict__ ad,
    const float* __restrict__ bc, const int* __restrict__ found,
    float* __restrict__ out)
{
    const int p = blockIdx.x * 256 + threadIdx.x;
    if (p >= N_PAIRS) return;
    float v = as[ps[p]] + ad[pd[p]] + bc[0];
    float sg = 1.f / (1.f + __expf(-v));
    out[p] = found[p] ? sg : 0.f;
}

extern "C" void kernel_launch(void* const* d_in, const int* in_sizes, int n_in,
                              void* d_out, int out_size, void* d_ws, size_t ws_size,
                              hipStream_t stream)
{
    const float* feat = (const float*)d_in[0];
    const float* W1   = (const float*)d_in[1];
    const float* al1  = (const float*)d_in[2];
    const float* ar1  = (const float*)d_in[3];
    const float* W2   = (const float*)d_in[4];
    const float* al2  = (const float*)d_in[5];
    const float* ar2  = (const float*)d_in[6];
    const float* Wc   = (const float*)d_in[7];
    const float* bc   = (const float*)d_in[8];
    const int* src    = (const int*)d_in[9];
    const int* dst    = (const int*)d_in[10];
    const int* psrc   = (const int*)d_in[11];
    const int* pdst   = (const int*)d_in[12];
    float* out = (float*)d_out;

    char* ws = (char*)d_ws;
    unsigned short* z  = (unsigned short*)ws;  ws += (size_t)N_NODES * HID * 2;
    unsigned short* h1 = (unsigned short*)ws;  ws += (size_t)N_NODES * HID * 2;
    float* el = (float*)ws;               ws += (size_t)N_NODES * 4;
    float* er = (float*)ws;               ws += (size_t)N_NODES * 4;
    float* as = (float*)ws;               ws += (size_t)N_NODES * 4;
    float* ad = (float*)ws;               ws += (size_t)N_NODES * 4;
    int* row_start = (int*)ws;            ws += (size_t)(N_NODES + 1) * 4;
    int* histHi = (int*)ws;               ws += (size_t)MHIST * 4;
    int* bsumsA = (int*)ws;               ws += (size_t)(SBG + 1) * 4;
    int* found = (int*)ws;                ws += (size_t)N_PAIRS * 4;
    ws = (char*)(((uintptr_t)ws + 255) & ~(uintptr_t)255);
    unsigned* pairs = (unsigned*)ws;      ws += (size_t)N_EDGES * 4;
    unsigned short* csr_src = (unsigned short*)ws;  ws += (size_t)N_EDGES * 2;
    ws = (char*)(((uintptr_t)ws + 255) & ~(uintptr_t)255);
    unsigned short* w1hi = (unsigned short*)ws;  ws += 8192 * 2;
    unsigned short* w1lo = (unsigned short*)ws;  ws += 8192 * 2;
    unsigned short* w2hi = (unsigned short*)ws;  ws += 4096 * 2;
    unsigned short* w2lo = (unsigned short*)ws;  ws += 4096 * 2;

    dim3 b64x4(64, 4);

    // 1) histogram + W prep
    hist_prep<<<NB1 + 32, 256, 0, stream>>>(dst, histHi, W1, W2, w1hi, w1lo, w2hi, w2lo);
    // 2) scan over MHIST (tiny)
    scan1g<<<SBG, 256, 0, stream>>>(histHi, bsumsA);
    // 3) bucket scatter || layer-1 GEMM (fused: gemm hides behind scatter)
    scatter_gemm1<<<NB1 + MB_GEMM, b64x4, 0, stream>>>(src, dst, histHi, bsumsA, pairs,
        feat, w1hi, w1lo, al1, ar1, z, el, er);
    // 4) segment sort -> row_start + csr_src (u16)
    seg_sort<<<NB1, 256, 0, stream>>>(pairs, histHi, bsumsA, row_start, csr_src);
    // 5) layer-1 aggregate
    agg1<<<NODE_BLOCKS, b64x4, 0, stream>>>(row_start, csr_src, el, er, z, h1);
    // 6) layer-2 GEMM || pair membership (fused: membership fills idle CUs)
    gemm2_member<<<MB_GEMM + MEMBER_BLOCKS, b64x4, 0, stream>>>(h1, w2hi, w2lo,
        al2, ar2, z, el, er, row_start, csr_src, psrc, pdst, found);
    // 7) layer-2 aggregate + head dots
    agg2<<<NODE_BLOCKS, b64x4, 0, stream>>>(row_start, csr_src, el, er, z, Wc, as, ad);
    // 8) final pair output
    pair_tiny<<<(N_PAIRS + 255) / 256, 256, 0, stream>>>(psrc, pdst, as, ad, bc, found, out);
}